// Round 1
// baseline (3122.152 us; speedup 1.0000x reference)
//
#include <hip/hip_runtime.h>

#define NF 128

// ---------------- dtype detect / decode ----------------
__global__ void detect_dtype_k(const void* __restrict__ ei, int n_check, int N,
                               int* __restrict__ flag) {
  __shared__ int cnt;
  if (threadIdx.x == 0) cnt = 0;
  __syncthreads();
  const long long* p = (const long long*)ei;
  int good = 0;
  for (int i = threadIdx.x; i < n_check; i += blockDim.x) {
    long long v = p[i];
    if (v >= 0 && v < (long long)N) good++;
  }
  atomicAdd(&cnt, good);
  __syncthreads();
  if (threadIdx.x == 0) flag[0] = (cnt > n_check / 2) ? 1 : 0;
}

__global__ void decode_edges_k(const void* __restrict__ ei, int E, int N,
                               const int* __restrict__ flag,
                               int* __restrict__ src, int* __restrict__ dst) {
  int is64 = flag[0];
  int stride = gridDim.x * blockDim.x;
  for (int e = blockIdx.x * blockDim.x + threadIdx.x; e < E; e += stride) {
    int s, d;
    if (is64) {
      s = (int)((const long long*)ei)[e];
      d = (int)((const long long*)ei)[(size_t)E + e];
    } else {
      s = ((const int*)ei)[e];
      d = ((const int*)ei)[(size_t)E + e];
    }
    s = min(max(s, 0), N - 1);
    d = min(max(d, 0), N - 1);
    src[e] = s;
    dst[e] = d;
  }
}

// ---------------- degree / norm ----------------
__global__ void deg_init_k(float* __restrict__ deg, int N) {
  int i = blockIdx.x * blockDim.x + threadIdx.x;
  if (i < N) deg[i] = 1.0f;  // self-loop
}

__global__ void deg_count_k(const int* __restrict__ dst, float* __restrict__ deg, int E) {
  int stride = gridDim.x * blockDim.x;
  for (int e = blockIdx.x * blockDim.x + threadIdx.x; e < E; e += stride)
    atomicAdd(&deg[dst[e]], 1.0f);
}

__global__ void dinv_k(const float* __restrict__ deg, float* __restrict__ dinv, int N) {
  int i = blockIdx.x * blockDim.x + threadIdx.x;
  if (i < N) dinv[i] = rsqrtf(deg[i]);
}

// ---------------- dense matmul: Y[N,128] = X[N,128] @ W[128,128] ----------------
__global__ __launch_bounds__(256) void matmul128_k(const float* __restrict__ X,
                                                   const float* __restrict__ W,
                                                   float* __restrict__ Y, int N) {
  __shared__ float Ws[NF * NF];
  __shared__ float Xs[8][NF];
  for (int i = threadIdx.x; i < NF * NF; i += 256) Ws[i] = W[i];
  int c  = threadIdx.x & 127;
  int rg = threadIdx.x >> 7;  // 0..1
  for (int base = blockIdx.x * 8; base < N; base += gridDim.x * 8) {
    __syncthreads();
    int nr = min(8, N - base);
    for (int i = threadIdx.x; i < nr * NF; i += 256)
      ((float*)Xs)[i] = X[(size_t)base * NF + i];
    __syncthreads();
    float a0 = 0.f, a1 = 0.f, a2 = 0.f, a3 = 0.f;
#pragma unroll 8
    for (int k4 = 0; k4 < 32; ++k4) {
      const float4 x0 = *(const float4*)&Xs[rg * 4 + 0][k4 * 4];
      const float4 x1 = *(const float4*)&Xs[rg * 4 + 1][k4 * 4];
      const float4 x2 = *(const float4*)&Xs[rg * 4 + 2][k4 * 4];
      const float4 x3 = *(const float4*)&Xs[rg * 4 + 3][k4 * 4];
      float w0 = Ws[(k4 * 4 + 0) * NF + c];
      float w1 = Ws[(k4 * 4 + 1) * NF + c];
      float w2 = Ws[(k4 * 4 + 2) * NF + c];
      float w3 = Ws[(k4 * 4 + 3) * NF + c];
      a0 += x0.x * w0 + x0.y * w1 + x0.z * w2 + x0.w * w3;
      a1 += x1.x * w0 + x1.y * w1 + x1.z * w2 + x1.w * w3;
      a2 += x2.x * w0 + x2.y * w1 + x2.z * w2 + x2.w * w3;
      a3 += x3.x * w0 + x3.y * w1 + x3.z * w2 + x3.w * w3;
    }
    int r0 = base + rg * 4;
    if (r0 + 0 < N) Y[(size_t)(r0 + 0) * NF + c] = a0;
    if (r0 + 1 < N) Y[(size_t)(r0 + 1) * NF + c] = a1;
    if (r0 + 2 < N) Y[(size_t)(r0 + 2) * NF + c] = a2;
    if (r0 + 3 < N) Y[(size_t)(r0 + 3) * NF + c] = a3;
  }
}

// ---------------- self-loop init: OUT[i,:] = H[i,:] * dinv[i]^2 ----------------
__global__ void selfinit_k(const float* __restrict__ H, const float* __restrict__ dinv,
                           float* __restrict__ OUT, int N) {
  int total = N * 32;  // float4 count
  int stride = gridDim.x * blockDim.x;
  for (int i = blockIdx.x * blockDim.x + threadIdx.x; i < total; i += stride) {
    int r = i >> 5;
    float di = dinv[r];
    float s = di * di;
    float4 v = ((const float4*)H)[i];
    v.x *= s; v.y *= s; v.z *= s; v.w *= s;
    ((float4*)OUT)[i] = v;
  }
}

// ---------------- edge scatter: OUT[d,:] += H[s,:] * dinv[s]*dinv[d] ----------------
__global__ __launch_bounds__(256) void scatter_k(const int* __restrict__ src,
                                                 const int* __restrict__ dst,
                                                 const float* __restrict__ dinv,
                                                 const float* __restrict__ H,
                                                 float* __restrict__ OUT, int E) {
  int lane = threadIdx.x & 63;
  int wid  = blockIdx.x * 4 + (threadIdx.x >> 6);
  int nw   = gridDim.x * 4;
  for (int e = wid; e < E; e += nw) {
    int s = src[e], d = dst[e];
    float nrm = dinv[s] * dinv[d];
    float2 hv = ((const float2*)H)[(size_t)s * 64 + lane];
    size_t o = (size_t)d * 128 + (size_t)lane * 2;
    atomicAdd(&OUT[o],     hv.x * nrm);
    atomicAdd(&OUT[o + 1], hv.y * nrm);
  }
}

// ---------------- bias + relu ----------------
__global__ void biasrelu_k(const float* __restrict__ IN, const float* __restrict__ b,
                           float* __restrict__ OUT, int N) {
  int total = N * 32;
  int stride = gridDim.x * blockDim.x;
  for (int i = blockIdx.x * blockDim.x + threadIdx.x; i < total; i += stride) {
    int c4 = i & 31;
    float4 bv = ((const float4*)b)[c4];
    float4 v = ((const float4*)IN)[i];
    v.x = fmaxf(v.x + bv.x, 0.f);
    v.y = fmaxf(v.y + bv.y, 0.f);
    v.z = fmaxf(v.z + bv.z, 0.f);
    v.w = fmaxf(v.w + bv.w, 0.f);
    ((float4*)OUT)[i] = v;
  }
}

// ---------------- final: out[i] = dot(H[i,:], Wl) + bl ----------------
__global__ void final_k(const float* __restrict__ H, const float* __restrict__ Wl,
                        const float* __restrict__ bl, float* __restrict__ out, int N) {
  __shared__ float wls[NF];
  if (threadIdx.x < NF) wls[threadIdx.x] = Wl[threadIdx.x];
  __syncthreads();
  int lane = threadIdx.x & 63;
  int wid  = blockIdx.x * 4 + (threadIdx.x >> 6);
  int nw   = gridDim.x * 4;
  for (int r = wid; r < N; r += nw) {
    float2 hv = ((const float2*)H)[(size_t)r * 64 + lane];
    float p = hv.x * wls[lane * 2] + hv.y * wls[lane * 2 + 1];
#pragma unroll
    for (int off = 32; off; off >>= 1) p += __shfl_xor(p, off);
    if (lane == 0) out[r] = p + bl[0];
  }
}

extern "C" void kernel_launch(void* const* d_in, const int* in_sizes, int n_in,
                              void* d_out, int out_size, void* d_ws, size_t ws_size,
                              hipStream_t stream) {
  const float* x  = (const float*)d_in[0];
  const void*  ei = d_in[1];
  const float* W1 = (const float*)d_in[2];
  const float* b1 = (const float*)d_in[3];
  const float* W2 = (const float*)d_in[4];
  const float* b2 = (const float*)d_in[5];
  const float* Wl = (const float*)d_in[6];
  const float* bl = (const float*)d_in[7];
  float* out = (float*)d_out;

  int N = in_sizes[0] / NF;
  int E = in_sizes[1] / 2;

  char* ws = (char*)d_ws;
  size_t off = 0;
  auto carve = [&](size_t bytes) {
    char* p = ws + off;
    off = (off + bytes + 255) & ~255ULL;
    return p;
  };
  int*   srcv = (int*)carve((size_t)E * 4);
  int*   dstv = (int*)carve((size_t)E * 4);
  float* deg  = (float*)carve((size_t)N * 4);
  float* dnv  = (float*)carve((size_t)N * 4);
  int*   flag = (int*)carve(4);
  float* bufA = (float*)carve((size_t)N * NF * 4);
  float* bufB = (float*)carve((size_t)N * NF * 4);

  int nblk = (N + 255) / 256;

  hipLaunchKernelGGL(detect_dtype_k, dim3(1), dim3(256), 0, stream, ei, 1024, N, flag);
  hipLaunchKernelGGL(decode_edges_k, dim3(2048), dim3(256), 0, stream, ei, E, N, flag, srcv, dstv);
  hipLaunchKernelGGL(deg_init_k, dim3(nblk), dim3(256), 0, stream, deg, N);
  hipLaunchKernelGGL(deg_count_k, dim3(2048), dim3(256), 0, stream, dstv, deg, E);
  hipLaunchKernelGGL(dinv_k, dim3(nblk), dim3(256), 0, stream, deg, dnv, N);

  // layer 1
  hipLaunchKernelGGL(matmul128_k, dim3(512), dim3(256), 0, stream, x, W1, bufA, N);
  hipLaunchKernelGGL(selfinit_k, dim3(4096), dim3(256), 0, stream, bufA, dnv, bufB, N);
  hipLaunchKernelGGL(scatter_k, dim3(8192), dim3(256), 0, stream, srcv, dstv, dnv, bufA, bufB, E);
  hipLaunchKernelGGL(biasrelu_k, dim3(4096), dim3(256), 0, stream, bufB, b1, bufA, N);

  // layer 2
  hipLaunchKernelGGL(matmul128_k, dim3(512), dim3(256), 0, stream, bufA, W2, bufB, N);
  hipLaunchKernelGGL(selfinit_k, dim3(4096), dim3(256), 0, stream, bufB, dnv, bufA, N);
  hipLaunchKernelGGL(scatter_k, dim3(8192), dim3(256), 0, stream, srcv, dstv, dnv, bufB, bufA, E);
  hipLaunchKernelGGL(biasrelu_k, dim3(4096), dim3(256), 0, stream, bufA, b2, bufB, N);

  // final projection
  hipLaunchKernelGGL(final_k, dim3(2048), dim3(256), 0, stream, bufB, Wl, bl, out, N);
}

// Round 2
// 824.908 us; speedup vs baseline: 3.7848x; 3.7848x over previous
//
#include <hip/hip_runtime.h>

#define NF 128

// ---------------- dtype detect / decode ----------------
__global__ void detect_dtype_k(const void* __restrict__ ei, int n_check, int N,
                               int* __restrict__ flag) {
  __shared__ int cnt;
  if (threadIdx.x == 0) cnt = 0;
  __syncthreads();
  const long long* p = (const long long*)ei;
  int good = 0;
  for (int i = threadIdx.x; i < n_check; i += blockDim.x) {
    long long v = p[i];
    if (v >= 0 && v < (long long)N) good++;
  }
  atomicAdd(&cnt, good);
  __syncthreads();
  if (threadIdx.x == 0) flag[0] = (cnt > n_check / 2) ? 1 : 0;
}

__global__ void decode_edges_k(const void* __restrict__ ei, int E, int N,
                               const int* __restrict__ flag,
                               int* __restrict__ src, int* __restrict__ dst) {
  int is64 = flag[0];
  int stride = gridDim.x * blockDim.x;
  for (int e = blockIdx.x * blockDim.x + threadIdx.x; e < E; e += stride) {
    int s, d;
    if (is64) {
      s = (int)((const long long*)ei)[e];
      d = (int)((const long long*)ei)[(size_t)E + e];
    } else {
      s = ((const int*)ei)[e];
      d = ((const int*)ei)[(size_t)E + e];
    }
    s = min(max(s, 0), N - 1);
    d = min(max(d, 0), N - 1);
    src[e] = s;
    dst[e] = d;
  }
}

// ---------------- CSR build ----------------
__global__ void zero_cnt_k(int* __restrict__ cnt, int N) {
  int i = blockIdx.x * blockDim.x + threadIdx.x;
  if (i < N) cnt[i] = 0;
}

__global__ void hist_k(const int* __restrict__ dst, int* __restrict__ cnt, int E) {
  int stride = gridDim.x * blockDim.x;
  for (int e = blockIdx.x * blockDim.x + threadIdx.x; e < E; e += stride)
    atomicAdd(&cnt[dst[e]], 1);
}

__global__ __launch_bounds__(256) void scan_block_k(const int* __restrict__ cnt,
                                                    int* __restrict__ rowptr,
                                                    int* __restrict__ bsum, int N) {
  __shared__ int tmp[256];
  int i = blockIdx.x * 256 + threadIdx.x;
  int v = (i < N) ? cnt[i] : 0;
  tmp[threadIdx.x] = v;
  __syncthreads();
  for (int o = 1; o < 256; o <<= 1) {
    int t = (threadIdx.x >= o) ? tmp[threadIdx.x - o] : 0;
    __syncthreads();
    tmp[threadIdx.x] += t;
    __syncthreads();
  }
  if (i < N) rowptr[i] = tmp[threadIdx.x] - v;  // exclusive
  if (threadIdx.x == 255) bsum[blockIdx.x] = tmp[255];
}

__global__ __launch_bounds__(512) void scan_top_k(int* __restrict__ bsum, int nb) {
  __shared__ int tmp[512];
  int v = (threadIdx.x < nb) ? bsum[threadIdx.x] : 0;
  tmp[threadIdx.x] = v;
  __syncthreads();
  for (int o = 1; o < 512; o <<= 1) {
    int t = (threadIdx.x >= o) ? tmp[threadIdx.x - o] : 0;
    __syncthreads();
    tmp[threadIdx.x] += t;
    __syncthreads();
  }
  if (threadIdx.x < nb) bsum[threadIdx.x] = tmp[threadIdx.x] - v;  // exclusive
}

__global__ void scan_add_k(int* __restrict__ rowptr, const int* __restrict__ bsum,
                           int* __restrict__ cursor, const int* __restrict__ cnt,
                           float* __restrict__ dinv, int N, int E) {
  int i = blockIdx.x * blockDim.x + threadIdx.x;
  if (i < N) {
    int r = rowptr[i] + bsum[i >> 8];
    rowptr[i] = r;
    cursor[i] = r;
    dinv[i] = rsqrtf((float)cnt[i] + 1.0f);  // +1 self-loop
  }
  if (i == 0) rowptr[N] = E;
}

__global__ void fill_k(const int* __restrict__ src, const int* __restrict__ dst,
                       int* __restrict__ cursor, int* __restrict__ csr, int E) {
  int stride = gridDim.x * blockDim.x;
  for (int e = blockIdx.x * blockDim.x + threadIdx.x; e < E; e += stride) {
    int pos = atomicAdd(&cursor[dst[e]], 1);
    csr[pos] = src[e];
  }
}

// ---------------- dense matmul: G[r,c] = (X @ W)[r,c] * dinv[r] ----------------
__global__ __launch_bounds__(256) void matmul128_k(const float* __restrict__ X,
                                                   const float* __restrict__ W,
                                                   const float* __restrict__ dinv,
                                                   float* __restrict__ Y, int N) {
  __shared__ float Ws[NF * NF];
  __shared__ float Xs[8][NF];
  for (int i = threadIdx.x; i < NF * NF; i += 256) Ws[i] = W[i];
  int c  = threadIdx.x & 127;
  int rg = threadIdx.x >> 7;  // 0..1
  for (int base = blockIdx.x * 8; base < N; base += gridDim.x * 8) {
    __syncthreads();
    int nr = min(8, N - base);
    for (int i = threadIdx.x; i < nr * NF; i += 256)
      ((float*)Xs)[i] = X[(size_t)base * NF + i];
    __syncthreads();
    float a0 = 0.f, a1 = 0.f, a2 = 0.f, a3 = 0.f;
#pragma unroll 8
    for (int k4 = 0; k4 < 32; ++k4) {
      const float4 x0 = *(const float4*)&Xs[rg * 4 + 0][k4 * 4];
      const float4 x1 = *(const float4*)&Xs[rg * 4 + 1][k4 * 4];
      const float4 x2 = *(const float4*)&Xs[rg * 4 + 2][k4 * 4];
      const float4 x3 = *(const float4*)&Xs[rg * 4 + 3][k4 * 4];
      float w0 = Ws[(k4 * 4 + 0) * NF + c];
      float w1 = Ws[(k4 * 4 + 1) * NF + c];
      float w2 = Ws[(k4 * 4 + 2) * NF + c];
      float w3 = Ws[(k4 * 4 + 3) * NF + c];
      a0 += x0.x * w0 + x0.y * w1 + x0.z * w2 + x0.w * w3;
      a1 += x1.x * w0 + x1.y * w1 + x1.z * w2 + x1.w * w3;
      a2 += x2.x * w0 + x2.y * w1 + x2.z * w2 + x2.w * w3;
      a3 += x3.x * w0 + x3.y * w1 + x3.z * w2 + x3.w * w3;
    }
    int r0 = base + rg * 4;
    if (r0 + 0 < N) Y[(size_t)(r0 + 0) * NF + c] = a0 * dinv[r0 + 0];
    if (r0 + 1 < N) Y[(size_t)(r0 + 1) * NF + c] = a1 * dinv[r0 + 1];
    if (r0 + 2 < N) Y[(size_t)(r0 + 2) * NF + c] = a2 * dinv[r0 + 2];
    if (r0 + 3 < N) Y[(size_t)(r0 + 3) * NF + c] = a3 * dinv[r0 + 3];
  }
}

// ------- gather aggregate: OUT[d,:] = relu(dinv[d]*(G[d,:] + sum_in G[s,:]) + b) -------
__global__ __launch_bounds__(256) void gather_agg_k(const int* __restrict__ rowptr,
                                                    const int* __restrict__ csr,
                                                    const float* __restrict__ dinv,
                                                    const float* __restrict__ G,
                                                    const float* __restrict__ b,
                                                    float* __restrict__ OUT, int N) {
  int lane = threadIdx.x & 63;
  int w    = blockIdx.x * 4 + (threadIdx.x >> 6);
  int nw   = gridDim.x * 4;
  float2 bv = ((const float2*)b)[lane];
  const float2* G2 = (const float2*)G;
  for (int d = w; d < N; d += nw) {
    int beg = rowptr[d], end = rowptr[d + 1];
    float2 acc = G2[(size_t)d * 64 + lane];  // self-loop term (already *dinv[d])
    int cnt = end - beg;
    int j = 0;
    while (j < cnt) {
      int chunk = min(cnt - j, 64);
      int idx = (lane < chunk) ? csr[beg + j + lane] : 0;
      int t = 0;
      for (; t + 4 <= chunk; t += 4) {
        int s0 = __shfl(idx, t + 0);
        int s1 = __shfl(idx, t + 1);
        int s2 = __shfl(idx, t + 2);
        int s3 = __shfl(idx, t + 3);
        float2 v0 = G2[(size_t)s0 * 64 + lane];
        float2 v1 = G2[(size_t)s1 * 64 + lane];
        float2 v2 = G2[(size_t)s2 * 64 + lane];
        float2 v3 = G2[(size_t)s3 * 64 + lane];
        acc.x += v0.x + v1.x + v2.x + v3.x;
        acc.y += v0.y + v1.y + v2.y + v3.y;
      }
      for (; t < chunk; ++t) {
        int s = __shfl(idx, t);
        float2 v = G2[(size_t)s * 64 + lane];
        acc.x += v.x;
        acc.y += v.y;
      }
      j += chunk;
    }
    float dd = dinv[d];
    float2 o;
    o.x = fmaxf(acc.x * dd + bv.x, 0.f);
    o.y = fmaxf(acc.y * dd + bv.y, 0.f);
    ((float2*)OUT)[(size_t)d * 64 + lane] = o;
  }
}

// ---------------- final: out[i] = dot(H[i,:], Wl) + bl ----------------
__global__ void final_k(const float* __restrict__ H, const float* __restrict__ Wl,
                        const float* __restrict__ bl, float* __restrict__ out, int N) {
  __shared__ float wls[NF];
  if (threadIdx.x < NF) wls[threadIdx.x] = Wl[threadIdx.x];
  __syncthreads();
  int lane = threadIdx.x & 63;
  int wid  = blockIdx.x * 4 + (threadIdx.x >> 6);
  int nw   = gridDim.x * 4;
  for (int r = wid; r < N; r += nw) {
    float2 hv = ((const float2*)H)[(size_t)r * 64 + lane];
    float p = hv.x * wls[lane * 2] + hv.y * wls[lane * 2 + 1];
#pragma unroll
    for (int off = 32; off; off >>= 1) p += __shfl_xor(p, off);
    if (lane == 0) out[r] = p + bl[0];
  }
}

extern "C" void kernel_launch(void* const* d_in, const int* in_sizes, int n_in,
                              void* d_out, int out_size, void* d_ws, size_t ws_size,
                              hipStream_t stream) {
  const float* x  = (const float*)d_in[0];
  const void*  ei = d_in[1];
  const float* W1 = (const float*)d_in[2];
  const float* b1 = (const float*)d_in[3];
  const float* W2 = (const float*)d_in[4];
  const float* b2 = (const float*)d_in[5];
  const float* Wl = (const float*)d_in[6];
  const float* bl = (const float*)d_in[7];
  float* out = (float*)d_out;

  int N = in_sizes[0] / NF;
  int E = in_sizes[1] / 2;

  char* ws = (char*)d_ws;
  size_t off = 0;
  auto carve = [&](size_t bytes) {
    char* p = ws + off;
    off = (off + bytes + 255) & ~255ULL;
    return p;
  };
  int*   srcv   = (int*)carve((size_t)E * 4);
  int*   dstv   = (int*)carve((size_t)E * 4);
  int*   csr    = (int*)carve((size_t)E * 4);
  int*   cnt    = (int*)carve((size_t)N * 4);
  int*   rowptr = (int*)carve((size_t)(N + 1) * 4);
  int*   cursor = (int*)carve((size_t)N * 4);
  float* dnv    = (float*)carve((size_t)N * 4);
  int*   bsum   = (int*)carve((size_t)4096 * 4);
  int*   flag   = (int*)carve(4);
  float* bufA   = (float*)carve((size_t)N * NF * 4);
  float* bufB   = (float*)carve((size_t)N * NF * 4);

  int nblk = (N + 255) / 256;  // 391 for N=100000 (<=512 for scan_top)

  hipLaunchKernelGGL(detect_dtype_k, dim3(1), dim3(256), 0, stream, ei, 1024, N, flag);
  hipLaunchKernelGGL(decode_edges_k, dim3(2048), dim3(256), 0, stream, ei, E, N, flag, srcv, dstv);

  // CSR build
  hipLaunchKernelGGL(zero_cnt_k, dim3(nblk), dim3(256), 0, stream, cnt, N);
  hipLaunchKernelGGL(hist_k, dim3(2048), dim3(256), 0, stream, dstv, cnt, E);
  hipLaunchKernelGGL(scan_block_k, dim3(nblk), dim3(256), 0, stream, cnt, rowptr, bsum, N);
  hipLaunchKernelGGL(scan_top_k, dim3(1), dim3(512), 0, stream, bsum, nblk);
  hipLaunchKernelGGL(scan_add_k, dim3(nblk), dim3(256), 0, stream, rowptr, bsum, cursor, cnt, dnv, N, E);
  hipLaunchKernelGGL(fill_k, dim3(2048), dim3(256), 0, stream, srcv, dstv, cursor, csr, E);

  // layer 1
  hipLaunchKernelGGL(matmul128_k, dim3(512), dim3(256), 0, stream, x, W1, dnv, bufA, N);
  hipLaunchKernelGGL(gather_agg_k, dim3(2048), dim3(256), 0, stream, rowptr, csr, dnv, bufA, b1, bufB, N);

  // layer 2
  hipLaunchKernelGGL(matmul128_k, dim3(512), dim3(256), 0, stream, bufB, W2, dnv, bufA, N);
  hipLaunchKernelGGL(gather_agg_k, dim3(2048), dim3(256), 0, stream, rowptr, csr, dnv, bufA, b2, bufB, N);

  // final projection
  hipLaunchKernelGGL(final_k, dim3(2048), dim3(256), 0, stream, bufB, Wl, bl, out, N);
}

// Round 5
// 615.141 us; speedup vs baseline: 5.0755x; 1.3410x over previous
//
#include <hip/hip_runtime.h>

#define NF 128

typedef __attribute__((ext_vector_type(8))) short short8v;
typedef __attribute__((ext_vector_type(4))) float f32x4;

__device__ __forceinline__ unsigned short f2bf(float x) {
  unsigned u = __builtin_bit_cast(unsigned, x);
  unsigned r = (u + 0x7FFFu + ((u >> 16) & 1u)) >> 16;
  return (unsigned short)r;
}
__device__ __forceinline__ float bf2f(unsigned short h) {
  unsigned u = ((unsigned)h) << 16;
  return __builtin_bit_cast(float, u);
}

// ---------------- dtype detect ----------------
__global__ void detect_dtype_k(const void* __restrict__ ei, int n_check, int N,
                               int* __restrict__ flag) {
  __shared__ int cnt;
  if (threadIdx.x == 0) cnt = 0;
  __syncthreads();
  const long long* p = (const long long*)ei;
  int good = 0;
  for (int i = threadIdx.x; i < n_check; i += blockDim.x) {
    long long v = p[i];
    if (v >= 0 && v < (long long)N) good++;
  }
  atomicAdd(&cnt, good);
  __syncthreads();
  if (threadIdx.x == 0) flag[0] = (cnt > n_check / 2) ? 1 : 0;
}

// ---------------- decode + degree histogram (fused) ----------------
__global__ void decode_hist_k(const void* __restrict__ ei, int E, int N,
                              const int* __restrict__ flag,
                              int* __restrict__ src, int* __restrict__ dst,
                              int* __restrict__ cnt) {
  int is64 = flag[0];
  int stride = gridDim.x * blockDim.x;
  for (int e = blockIdx.x * blockDim.x + threadIdx.x; e < E; e += stride) {
    int s, d;
    if (is64) {
      s = (int)((const long long*)ei)[e];
      d = (int)((const long long*)ei)[(size_t)E + e];
    } else {
      s = ((const int*)ei)[e];
      d = ((const int*)ei)[(size_t)E + e];
    }
    s = min(max(s, 0), N - 1);
    d = min(max(d, 0), N - 1);
    src[e] = s;
    dst[e] = d;
    atomicAdd(&cnt[d], 1);
  }
}

__global__ void zero_cnt_k(int* __restrict__ cnt, int N) {
  int i = blockIdx.x * blockDim.x + threadIdx.x;
  if (i < N) cnt[i] = 0;
}

// ---------------- scan for CSR rowptr ----------------
__global__ __launch_bounds__(256) void scan_block_k(const int* __restrict__ cnt,
                                                    int* __restrict__ rowptr,
                                                    int* __restrict__ bsum, int N) {
  __shared__ int tmp[256];
  int i = blockIdx.x * 256 + threadIdx.x;
  int v = (i < N) ? cnt[i] : 0;
  tmp[threadIdx.x] = v;
  __syncthreads();
  for (int o = 1; o < 256; o <<= 1) {
    int t = (threadIdx.x >= o) ? tmp[threadIdx.x - o] : 0;
    __syncthreads();
    tmp[threadIdx.x] += t;
    __syncthreads();
  }
  if (i < N) rowptr[i] = tmp[threadIdx.x] - v;  // exclusive
  if (threadIdx.x == 255) bsum[blockIdx.x] = tmp[255];
}

__global__ __launch_bounds__(512) void scan_top_k(int* __restrict__ bsum, int nb) {
  __shared__ int tmp[512];
  int v = (threadIdx.x < nb) ? bsum[threadIdx.x] : 0;
  tmp[threadIdx.x] = v;
  __syncthreads();
  for (int o = 1; o < 512; o <<= 1) {
    int t = (threadIdx.x >= o) ? tmp[threadIdx.x - o] : 0;
    __syncthreads();
    tmp[threadIdx.x] += t;
    __syncthreads();
  }
  if (threadIdx.x < nb) bsum[threadIdx.x] = tmp[threadIdx.x] - v;  // exclusive
}

__global__ void scan_add_k(int* __restrict__ rowptr, const int* __restrict__ bsum,
                           int* __restrict__ cursor, const int* __restrict__ cnt,
                           float* __restrict__ dinv, int N, int E) {
  int i = blockIdx.x * blockDim.x + threadIdx.x;
  if (i < N) {
    int r = rowptr[i] + bsum[i >> 8];
    rowptr[i] = r;
    cursor[i] = r;
    dinv[i] = rsqrtf((float)cnt[i] + 1.0f);  // +1 self-loop
  }
  if (i == 0) rowptr[N] = E;
}

__global__ void fill_k(const int* __restrict__ src, const int* __restrict__ dst,
                       int* __restrict__ cursor, int* __restrict__ csr, int E) {
  int stride = gridDim.x * blockDim.x;
  for (int e = blockIdx.x * blockDim.x + threadIdx.x; e < E; e += stride) {
    int pos = atomicAdd(&cursor[dst[e]], 1);
    csr[pos] = src[e];
  }
}

// ---------------- pack W into MFMA B-fragment order (hi/lo bf16) ----------------
// frag-lane t in [0,2048): ct=t>>8, kc=(t>>6)&3, lane=t&63
// element e: B[k = kc*32 + 8*(lane>>4) + e][col = ct*16 + (lane&15)]
__global__ void packW_k(const float* __restrict__ W, unsigned short* __restrict__ PH,
                        unsigned short* __restrict__ PL) {
  int t = blockIdx.x * blockDim.x + threadIdx.x;
  if (t >= 2048) return;
  int ct = t >> 8, kc = (t >> 6) & 3, lane = t & 63;
  int k0 = kc * 32 + 8 * (lane >> 4);
  int col = ct * 16 + (lane & 15);
#pragma unroll
  for (int e = 0; e < 8; ++e) {
    float w = W[(size_t)(k0 + e) * NF + col];
    unsigned short h = f2bf(w);
    float lo = w - bf2f(h);
    PH[(size_t)t * 8 + e] = h;
    PL[(size_t)t * 8 + e] = f2bf(lo);
  }
}

// ---------------- MFMA matmul: Y = (X @ W) * dinv[row], bf16x3 split ----------------
__global__ __launch_bounds__(256) void mm_mfma_k(const float* __restrict__ X,
                                                 const unsigned short* __restrict__ WPH,
                                                 const unsigned short* __restrict__ WPL,
                                                 const float* __restrict__ dinv,
                                                 float* __restrict__ Y, int N) {
  int lane = threadIdx.x & 63;
  int wv = threadIdx.x >> 6;
  int row0 = blockIdx.x * 64 + wv * 16;
  if (row0 >= N) return;
  int ar = min(row0 + (lane & 15), N - 1);
  const float* xp = X + (size_t)ar * NF + 8 * (lane >> 4);
  short8v Ah[4], Al[4];
#pragma unroll
  for (int kc = 0; kc < 4; ++kc) {
    float4 v0 = *(const float4*)(xp + kc * 32);
    float4 v1 = *(const float4*)(xp + kc * 32 + 4);
    float xv[8] = {v0.x, v0.y, v0.z, v0.w, v1.x, v1.y, v1.z, v1.w};
#pragma unroll
    for (int e = 0; e < 8; ++e) {
      unsigned short h = f2bf(xv[e]);
      float lo = xv[e] - bf2f(h);
      Ah[kc][e] = (short)h;
      Al[kc][e] = (short)f2bf(lo);
    }
  }
  int rbase = row0 + (lane >> 4) * 4;
  float dv[4];
#pragma unroll
  for (int j = 0; j < 4; ++j) dv[j] = (rbase + j < N) ? dinv[rbase + j] : 0.f;
  const short8v* BH = (const short8v*)WPH;
  const short8v* BL = (const short8v*)WPL;
  int c = (lane & 15);
#pragma unroll
  for (int ct = 0; ct < 8; ++ct) {
    f32x4 acc = {0.f, 0.f, 0.f, 0.f};
#pragma unroll
    for (int kc = 0; kc < 4; ++kc) {
      short8v bh = BH[(ct * 4 + kc) * 64 + lane];
      short8v bl = BL[(ct * 4 + kc) * 64 + lane];
      acc = __builtin_amdgcn_mfma_f32_16x16x32_bf16(Ah[kc], bh, acc, 0, 0, 0);
      acc = __builtin_amdgcn_mfma_f32_16x16x32_bf16(Ah[kc], bl, acc, 0, 0, 0);
      acc = __builtin_amdgcn_mfma_f32_16x16x32_bf16(Al[kc], bh, acc, 0, 0, 0);
    }
#pragma unroll
    for (int j = 0; j < 4; ++j) {
      int r = rbase + j;
      if (r < N) Y[(size_t)r * NF + ct * 16 + c] = acc[j] * dv[j];
    }
  }
}

// ------- gather aggregate: OUT[d,:] = relu(dinv[d]*(G[d,:] + sum_in G[s,:]) + b) -------
__global__ __launch_bounds__(256) void gather_agg_k(const int* __restrict__ rowptr,
                                                    const int* __restrict__ csr,
                                                    const float* __restrict__ dinv,
                                                    const float* __restrict__ G,
                                                    const float* __restrict__ b,
                                                    float* __restrict__ OUT, int N) {
  int lane = threadIdx.x & 63;
  int w    = blockIdx.x * 4 + (threadIdx.x >> 6);
  int nw   = gridDim.x * 4;
  float2 bv = ((const float2*)b)[lane];
  const float2* G2 = (const float2*)G;
  for (int d = w; d < N; d += nw) {
    int beg = rowptr[d], end = rowptr[d + 1];
    float2 acc = G2[(size_t)d * 64 + lane];  // self-loop term (already *dinv[d])
    int cnt = end - beg;
    int j = 0;
    while (j < cnt) {
      int chunk = min(cnt - j, 64);
      int idx = (lane < chunk) ? csr[beg + j + lane] : 0;
      int t = 0;
      for (; t + 8 <= chunk; t += 8) {
        int s0 = __shfl(idx, t + 0);
        int s1 = __shfl(idx, t + 1);
        int s2 = __shfl(idx, t + 2);
        int s3 = __shfl(idx, t + 3);
        int s4 = __shfl(idx, t + 4);
        int s5 = __shfl(idx, t + 5);
        int s6 = __shfl(idx, t + 6);
        int s7 = __shfl(idx, t + 7);
        float2 v0 = G2[(size_t)s0 * 64 + lane];
        float2 v1 = G2[(size_t)s1 * 64 + lane];
        float2 v2 = G2[(size_t)s2 * 64 + lane];
        float2 v3 = G2[(size_t)s3 * 64 + lane];
        float2 v4 = G2[(size_t)s4 * 64 + lane];
        float2 v5 = G2[(size_t)s5 * 64 + lane];
        float2 v6 = G2[(size_t)s6 * 64 + lane];
        float2 v7 = G2[(size_t)s7 * 64 + lane];
        acc.x += (v0.x + v1.x) + (v2.x + v3.x) + ((v4.x + v5.x) + (v6.x + v7.x));
        acc.y += (v0.y + v1.y) + (v2.y + v3.y) + ((v4.y + v5.y) + (v6.y + v7.y));
      }
      for (; t < chunk; ++t) {
        int s = __shfl(idx, t);
        float2 v = G2[(size_t)s * 64 + lane];
        acc.x += v.x;
        acc.y += v.y;
      }
      j += chunk;
    }
    float dd = dinv[d];
    float2 o;
    o.x = fmaxf(acc.x * dd + bv.x, 0.f);
    o.y = fmaxf(acc.y * dd + bv.y, 0.f);
    ((float2*)OUT)[(size_t)d * 64 + lane] = o;
  }
}

// ---------------- final: out[i] = dot(H[i,:], Wl) + bl ----------------
__global__ void final_k(const float* __restrict__ H, const float* __restrict__ Wl,
                        const float* __restrict__ bl, float* __restrict__ out, int N) {
  __shared__ float wls[NF];
  if (threadIdx.x < NF) wls[threadIdx.x] = Wl[threadIdx.x];
  __syncthreads();
  int lane = threadIdx.x & 63;
  int wid  = blockIdx.x * 4 + (threadIdx.x >> 6);
  int nw   = gridDim.x * 4;
  for (int r = wid; r < N; r += nw) {
    float2 hv = ((const float2*)H)[(size_t)r * 64 + lane];
    float p = hv.x * wls[lane * 2] + hv.y * wls[lane * 2 + 1];
#pragma unroll
    for (int off = 32; off; off >>= 1) p += __shfl_xor(p, off);
    if (lane == 0) out[r] = p + bl[0];
  }
}

extern "C" void kernel_launch(void* const* d_in, const int* in_sizes, int n_in,
                              void* d_out, int out_size, void* d_ws, size_t ws_size,
                              hipStream_t stream) {
  const float* x  = (const float*)d_in[0];
  const void*  ei = d_in[1];
  const float* W1 = (const float*)d_in[2];
  const float* b1 = (const float*)d_in[3];
  const float* W2 = (const float*)d_in[4];
  const float* b2 = (const float*)d_in[5];
  const float* Wl = (const float*)d_in[6];
  const float* bl = (const float*)d_in[7];
  float* out = (float*)d_out;

  int N = in_sizes[0] / NF;
  int E = in_sizes[1] / 2;

  char* ws = (char*)d_ws;
  size_t off = 0;
  auto carve = [&](size_t bytes) {
    char* p = ws + off;
    off = (off + bytes + 255) & ~255ULL;
    return p;
  };
  int*   srcv   = (int*)carve((size_t)E * 4);
  int*   dstv   = (int*)carve((size_t)E * 4);
  int*   csr    = (int*)carve((size_t)E * 4);
  int*   cnt    = (int*)carve((size_t)N * 4);
  int*   rowptr = (int*)carve((size_t)(N + 1) * 4);
  int*   cursor = (int*)carve((size_t)N * 4);
  float* dnv    = (float*)carve((size_t)N * 4);
  int*   bsum   = (int*)carve((size_t)4096 * 4);
  int*   flag   = (int*)carve(4);
  unsigned short* W1h = (unsigned short*)carve(16384 * 2);
  unsigned short* W1l = (unsigned short*)carve(16384 * 2);
  unsigned short* W2h = (unsigned short*)carve(16384 * 2);
  unsigned short* W2l = (unsigned short*)carve(16384 * 2);
  float* bufA   = (float*)carve((size_t)N * NF * 4);
  float* bufB   = (float*)carve((size_t)N * NF * 4);

  int nblk = (N + 255) / 256;  // 391 for N=100000 (<=512 for scan_top)
  int mmblk = (N + 63) / 64;

  hipLaunchKernelGGL(detect_dtype_k, dim3(1), dim3(256), 0, stream, ei, 1024, N, flag);
  hipLaunchKernelGGL(zero_cnt_k, dim3(nblk), dim3(256), 0, stream, cnt, N);
  hipLaunchKernelGGL(decode_hist_k, dim3(2048), dim3(256), 0, stream, ei, E, N, flag, srcv, dstv, cnt);

  // CSR build
  hipLaunchKernelGGL(scan_block_k, dim3(nblk), dim3(256), 0, stream, cnt, rowptr, bsum, N);
  hipLaunchKernelGGL(scan_top_k, dim3(1), dim3(512), 0, stream, bsum, nblk);
  hipLaunchKernelGGL(scan_add_k, dim3(nblk), dim3(256), 0, stream, rowptr, bsum, cursor, cnt, dnv, N, E);
  hipLaunchKernelGGL(fill_k, dim3(2048), dim3(256), 0, stream, srcv, dstv, cursor, csr, E);

  // pack weights
  hipLaunchKernelGGL(packW_k, dim3(8), dim3(256), 0, stream, W1, W1h, W1l);
  hipLaunchKernelGGL(packW_k, dim3(8), dim3(256), 0, stream, W2, W2h, W2l);

  // layer 1
  hipLaunchKernelGGL(mm_mfma_k, dim3(mmblk), dim3(256), 0, stream, x, W1h, W1l, dnv, bufA, N);
  hipLaunchKernelGGL(gather_agg_k, dim3(2048), dim3(256), 0, stream, rowptr, csr, dnv, bufA, b1, bufB, N);

  // layer 2
  hipLaunchKernelGGL(mm_mfma_k, dim3(mmblk), dim3(256), 0, stream, bufB, W2h, W2l, dnv, bufA, N);
  hipLaunchKernelGGL(gather_agg_k, dim3(2048), dim3(256), 0, stream, rowptr, csr, dnv, bufA, b2, bufB, N);

  // final projection
  hipLaunchKernelGGL(final_k, dim3(2048), dim3(256), 0, stream, bufB, Wl, bl, out, N);
}

// Round 6
// 600.374 us; speedup vs baseline: 5.2003x; 1.0246x over previous
//
#include <hip/hip_runtime.h>

#define NF 128

typedef __attribute__((ext_vector_type(8))) short short8v;
typedef __attribute__((ext_vector_type(4))) float f32x4;

__device__ __forceinline__ unsigned short f2bf(float x) {
  unsigned u = __builtin_bit_cast(unsigned, x);
  unsigned r = (u + 0x7FFFu + ((u >> 16) & 1u)) >> 16;
  return (unsigned short)r;
}
__device__ __forceinline__ float bf2f(unsigned short h) {
  unsigned u = ((unsigned)h) << 16;
  return __builtin_bit_cast(float, u);
}

// ---------------- zero cnt + dtype detect (merged) ----------------
__global__ void init_detect_k(const void* __restrict__ ei, int n_check, int N,
                              int* __restrict__ flag, int* __restrict__ cnt) {
  int i = blockIdx.x * blockDim.x + threadIdx.x;
  if (i < N) cnt[i] = 0;
  if (blockIdx.x == 0) {
    __shared__ int c;
    if (threadIdx.x == 0) c = 0;
    __syncthreads();
    const long long* p = (const long long*)ei;
    int good = 0;
    for (int k = threadIdx.x; k < n_check; k += blockDim.x) {
      long long v = p[k];
      if (v >= 0 && v < (long long)N) good++;
    }
    atomicAdd(&c, good);
    __syncthreads();
    if (threadIdx.x == 0) flag[0] = (c > n_check / 2) ? 1 : 0;
  }
}

// ---------------- decode + degree histogram (fused) ----------------
__global__ void decode_hist_k(const void* __restrict__ ei, int E, int N,
                              const int* __restrict__ flag,
                              int* __restrict__ src, int* __restrict__ dst,
                              int* __restrict__ cnt) {
  int is64 = flag[0];
  int stride = gridDim.x * blockDim.x;
  for (int e = blockIdx.x * blockDim.x + threadIdx.x; e < E; e += stride) {
    int s, d;
    if (is64) {
      s = (int)((const long long*)ei)[e];
      d = (int)((const long long*)ei)[(size_t)E + e];
    } else {
      s = ((const int*)ei)[e];
      d = ((const int*)ei)[(size_t)E + e];
    }
    s = min(max(s, 0), N - 1);
    d = min(max(d, 0), N - 1);
    src[e] = s;
    dst[e] = d;
    atomicAdd(&cnt[d], 1);
  }
}

// ---------------- scan for CSR rowptr ----------------
__global__ __launch_bounds__(256) void scan_block_k(const int* __restrict__ cnt,
                                                    int* __restrict__ rowptr,
                                                    int* __restrict__ bsum, int N) {
  __shared__ int tmp[256];
  int i = blockIdx.x * 256 + threadIdx.x;
  int v = (i < N) ? cnt[i] : 0;
  tmp[threadIdx.x] = v;
  __syncthreads();
  for (int o = 1; o < 256; o <<= 1) {
    int t = (threadIdx.x >= o) ? tmp[threadIdx.x - o] : 0;
    __syncthreads();
    tmp[threadIdx.x] += t;
    __syncthreads();
  }
  if (i < N) rowptr[i] = tmp[threadIdx.x] - v;  // exclusive
  if (threadIdx.x == 255) bsum[blockIdx.x] = tmp[255];
}

__global__ __launch_bounds__(512) void scan_top_k(int* __restrict__ bsum, int nb) {
  __shared__ int tmp[512];
  int v = (threadIdx.x < nb) ? bsum[threadIdx.x] : 0;
  tmp[threadIdx.x] = v;
  __syncthreads();
  for (int o = 1; o < 512; o <<= 1) {
    int t = (threadIdx.x >= o) ? tmp[threadIdx.x - o] : 0;
    __syncthreads();
    tmp[threadIdx.x] += t;
    __syncthreads();
  }
  if (threadIdx.x < nb) bsum[threadIdx.x] = tmp[threadIdx.x] - v;  // exclusive
}

__global__ void scan_add_k(int* __restrict__ rowptr, const int* __restrict__ bsum,
                           int* __restrict__ cursor, const int* __restrict__ cnt,
                           float* __restrict__ dinv, int N, int E) {
  int i = blockIdx.x * blockDim.x + threadIdx.x;
  if (i < N) {
    int r = rowptr[i] + bsum[i >> 8];
    rowptr[i] = r;
    cursor[i] = r;
    dinv[i] = rsqrtf((float)cnt[i] + 1.0f);  // +1 self-loop
  }
  if (i == 0) rowptr[N] = E;
}

__global__ void fill_k(const int* __restrict__ src, const int* __restrict__ dst,
                       int* __restrict__ cursor, int* __restrict__ csr, int E) {
  int stride = gridDim.x * blockDim.x;
  for (int e = blockIdx.x * blockDim.x + threadIdx.x; e < E; e += stride) {
    int pos = atomicAdd(&cursor[dst[e]], 1);
    __builtin_nontemporal_store(src[e], &csr[pos]);
  }
}

// ---------------- pack W1,W2 into MFMA B-fragment order (hi/lo bf16) ----------------
// frag-lane t in [0,2048): ct=t>>8, kc=(t>>6)&3, lane=t&63
// element e: B[k = kc*32 + 8*(lane>>4) + e][col = ct*16 + (lane&15)]
__global__ void packW2_k(const float* __restrict__ W1, const float* __restrict__ W2,
                         unsigned short* __restrict__ PH1, unsigned short* __restrict__ PL1,
                         unsigned short* __restrict__ PH2, unsigned short* __restrict__ PL2) {
  int t = blockIdx.x * blockDim.x + threadIdx.x;
  if (t >= 4096) return;
  const float* W = (t < 2048) ? W1 : W2;
  unsigned short* PH = (t < 2048) ? PH1 : PH2;
  unsigned short* PL = (t < 2048) ? PL1 : PL2;
  int tt = t & 2047;
  int ct = tt >> 8, kc = (tt >> 6) & 3, lane = tt & 63;
  int k0 = kc * 32 + 8 * (lane >> 4);
  int col = ct * 16 + (lane & 15);
#pragma unroll
  for (int e = 0; e < 8; ++e) {
    float w = W[(size_t)(k0 + e) * NF + col];
    unsigned short h = f2bf(w);
    float lo = w - bf2f(h);
    PH[(size_t)tt * 8 + e] = h;
    PL[(size_t)tt * 8 + e] = f2bf(lo);
  }
}

// ---------------- MFMA matmul: Y = (X @ W) * dinv[row], bf16x3 split ----------------
__global__ __launch_bounds__(256) void mm_mfma_k(const float* __restrict__ X,
                                                 const unsigned short* __restrict__ WPH,
                                                 const unsigned short* __restrict__ WPL,
                                                 const float* __restrict__ dinv,
                                                 float* __restrict__ Y, int N) {
  int lane = threadIdx.x & 63;
  int wv = threadIdx.x >> 6;
  int row0 = blockIdx.x * 64 + wv * 16;
  if (row0 >= N) return;
  int ar = min(row0 + (lane & 15), N - 1);
  const float* xp = X + (size_t)ar * NF + 8 * (lane >> 4);
  short8v Ah[4], Al[4];
#pragma unroll
  for (int kc = 0; kc < 4; ++kc) {
    float4 v0 = *(const float4*)(xp + kc * 32);
    float4 v1 = *(const float4*)(xp + kc * 32 + 4);
    float xv[8] = {v0.x, v0.y, v0.z, v0.w, v1.x, v1.y, v1.z, v1.w};
#pragma unroll
    for (int e = 0; e < 8; ++e) {
      unsigned short h = f2bf(xv[e]);
      float lo = xv[e] - bf2f(h);
      Ah[kc][e] = (short)h;
      Al[kc][e] = (short)f2bf(lo);
    }
  }
  int rbase = row0 + (lane >> 4) * 4;
  float dv[4];
#pragma unroll
  for (int j = 0; j < 4; ++j) dv[j] = (rbase + j < N) ? dinv[rbase + j] : 0.f;
  const short8v* BH = (const short8v*)WPH;
  const short8v* BL = (const short8v*)WPL;
  int c = (lane & 15);
#pragma unroll
  for (int ct = 0; ct < 8; ++ct) {
    f32x4 acc = {0.f, 0.f, 0.f, 0.f};
#pragma unroll
    for (int kc = 0; kc < 4; ++kc) {
      short8v bh = BH[(ct * 4 + kc) * 64 + lane];
      short8v bl = BL[(ct * 4 + kc) * 64 + lane];
      acc = __builtin_amdgcn_mfma_f32_16x16x32_bf16(Ah[kc], bh, acc, 0, 0, 0);
      acc = __builtin_amdgcn_mfma_f32_16x16x32_bf16(Ah[kc], bl, acc, 0, 0, 0);
      acc = __builtin_amdgcn_mfma_f32_16x16x32_bf16(Al[kc], bh, acc, 0, 0, 0);
    }
#pragma unroll
    for (int j = 0; j < 4; ++j) {
      int r = rbase + j;
      if (r < N) Y[(size_t)r * NF + ct * 16 + c] = acc[j] * dv[j];
    }
  }
}

// ------- gather aggregate (float4, 2 rows/wave): OUT[d,:] = relu(dinv[d]*(G[d,:]+sum G[s,:])+b) -------
__global__ __launch_bounds__(256) void gather_agg4_k(const int* __restrict__ rowptr,
                                                     const int* __restrict__ csr,
                                                     const float* __restrict__ dinv,
                                                     const float* __restrict__ G,
                                                     const float* __restrict__ b,
                                                     float* __restrict__ OUT, int N) {
  int lane = threadIdx.x & 63;
  int half = lane >> 5;
  int l32  = lane & 31;
  int w    = blockIdx.x * 4 + (threadIdx.x >> 6);
  int nw   = gridDim.x * 4;
  const float4* G4 = (const float4*)G;
  float4 bv = ((const float4*)b)[l32];
  for (int d0 = w * 2; d0 < N; d0 += nw * 2) {
    int d = d0 + half;
    if (d < N) {
      int beg = rowptr[d], end = rowptr[d + 1];
      float4 acc = G4[(size_t)d * 32 + l32];  // self-loop (already *dinv[d])
      int cnt = end - beg;
      int j = 0;
      while (j < cnt) {
        int chunk = min(cnt - j, 32);
        int idx = (l32 < chunk) ? csr[beg + j + l32] : 0;
        int t = 0;
        for (; t + 8 <= chunk; t += 8) {
          int s0 = __shfl(idx, t + 0, 32);
          int s1 = __shfl(idx, t + 1, 32);
          int s2 = __shfl(idx, t + 2, 32);
          int s3 = __shfl(idx, t + 3, 32);
          int s4 = __shfl(idx, t + 4, 32);
          int s5 = __shfl(idx, t + 5, 32);
          int s6 = __shfl(idx, t + 6, 32);
          int s7 = __shfl(idx, t + 7, 32);
          float4 v0 = G4[(size_t)s0 * 32 + l32];
          float4 v1 = G4[(size_t)s1 * 32 + l32];
          float4 v2 = G4[(size_t)s2 * 32 + l32];
          float4 v3 = G4[(size_t)s3 * 32 + l32];
          float4 v4 = G4[(size_t)s4 * 32 + l32];
          float4 v5 = G4[(size_t)s5 * 32 + l32];
          float4 v6 = G4[(size_t)s6 * 32 + l32];
          float4 v7 = G4[(size_t)s7 * 32 + l32];
          acc.x += (v0.x + v1.x) + (v2.x + v3.x) + ((v4.x + v5.x) + (v6.x + v7.x));
          acc.y += (v0.y + v1.y) + (v2.y + v3.y) + ((v4.y + v5.y) + (v6.y + v7.y));
          acc.z += (v0.z + v1.z) + (v2.z + v3.z) + ((v4.z + v5.z) + (v6.z + v7.z));
          acc.w += (v0.w + v1.w) + (v2.w + v3.w) + ((v4.w + v5.w) + (v6.w + v7.w));
        }
        for (; t < chunk; ++t) {
          int s = __shfl(idx, t, 32);
          float4 v = G4[(size_t)s * 32 + l32];
          acc.x += v.x; acc.y += v.y; acc.z += v.z; acc.w += v.w;
        }
        j += chunk;
      }
      float dd = dinv[d];
      float4 o;
      o.x = fmaxf(acc.x * dd + bv.x, 0.f);
      o.y = fmaxf(acc.y * dd + bv.y, 0.f);
      o.z = fmaxf(acc.z * dd + bv.z, 0.f);
      o.w = fmaxf(acc.w * dd + bv.w, 0.f);
      ((float4*)OUT)[(size_t)d * 32 + l32] = o;
    }
  }
}

// ------- layer-2 gather fused with final projection: out[d] = dot(relu(...), Wl) + bl -------
__global__ __launch_bounds__(256) void gather_final4_k(const int* __restrict__ rowptr,
                                                       const int* __restrict__ csr,
                                                       const float* __restrict__ dinv,
                                                       const float* __restrict__ G,
                                                       const float* __restrict__ b,
                                                       const float* __restrict__ Wl,
                                                       const float* __restrict__ bl,
                                                       float* __restrict__ out, int N) {
  int lane = threadIdx.x & 63;
  int half = lane >> 5;
  int l32  = lane & 31;
  int w    = blockIdx.x * 4 + (threadIdx.x >> 6);
  int nw   = gridDim.x * 4;
  const float4* G4 = (const float4*)G;
  float4 bv = ((const float4*)b)[l32];
  float4 wv = ((const float4*)Wl)[l32];
  float blv = bl[0];
  for (int d0 = w * 2; d0 < N; d0 += nw * 2) {
    int d = d0 + half;
    if (d < N) {
      int beg = rowptr[d], end = rowptr[d + 1];
      float4 acc = G4[(size_t)d * 32 + l32];
      int cnt = end - beg;
      int j = 0;
      while (j < cnt) {
        int chunk = min(cnt - j, 32);
        int idx = (l32 < chunk) ? csr[beg + j + l32] : 0;
        int t = 0;
        for (; t + 8 <= chunk; t += 8) {
          int s0 = __shfl(idx, t + 0, 32);
          int s1 = __shfl(idx, t + 1, 32);
          int s2 = __shfl(idx, t + 2, 32);
          int s3 = __shfl(idx, t + 3, 32);
          int s4 = __shfl(idx, t + 4, 32);
          int s5 = __shfl(idx, t + 5, 32);
          int s6 = __shfl(idx, t + 6, 32);
          int s7 = __shfl(idx, t + 7, 32);
          float4 v0 = G4[(size_t)s0 * 32 + l32];
          float4 v1 = G4[(size_t)s1 * 32 + l32];
          float4 v2 = G4[(size_t)s2 * 32 + l32];
          float4 v3 = G4[(size_t)s3 * 32 + l32];
          float4 v4 = G4[(size_t)s4 * 32 + l32];
          float4 v5 = G4[(size_t)s5 * 32 + l32];
          float4 v6 = G4[(size_t)s6 * 32 + l32];
          float4 v7 = G4[(size_t)s7 * 32 + l32];
          acc.x += (v0.x + v1.x) + (v2.x + v3.x) + ((v4.x + v5.x) + (v6.x + v7.x));
          acc.y += (v0.y + v1.y) + (v2.y + v3.y) + ((v4.y + v5.y) + (v6.y + v7.y));
          acc.z += (v0.z + v1.z) + (v2.z + v3.z) + ((v4.z + v5.z) + (v6.z + v7.z));
          acc.w += (v0.w + v1.w) + (v2.w + v3.w) + ((v4.w + v5.w) + (v6.w + v7.w));
        }
        for (; t < chunk; ++t) {
          int s = __shfl(idx, t, 32);
          float4 v = G4[(size_t)s * 32 + l32];
          acc.x += v.x; acc.y += v.y; acc.z += v.z; acc.w += v.w;
        }
        j += chunk;
      }
      float dd = dinv[d];
      float p = fmaxf(acc.x * dd + bv.x, 0.f) * wv.x
              + fmaxf(acc.y * dd + bv.y, 0.f) * wv.y
              + fmaxf(acc.z * dd + bv.z, 0.f) * wv.z
              + fmaxf(acc.w * dd + bv.w, 0.f) * wv.w;
#pragma unroll
      for (int off = 16; off; off >>= 1) p += __shfl_xor(p, off, 32);
      if (l32 == 0) out[d] = p + blv;
    }
  }
}

extern "C" void kernel_launch(void* const* d_in, const int* in_sizes, int n_in,
                              void* d_out, int out_size, void* d_ws, size_t ws_size,
                              hipStream_t stream) {
  const float* x  = (const float*)d_in[0];
  const void*  ei = d_in[1];
  const float* W1 = (const float*)d_in[2];
  const float* b1 = (const float*)d_in[3];
  const float* W2 = (const float*)d_in[4];
  const float* b2 = (const float*)d_in[5];
  const float* Wl = (const float*)d_in[6];
  const float* bl = (const float*)d_in[7];
  float* out = (float*)d_out;

  int N = in_sizes[0] / NF;
  int E = in_sizes[1] / 2;

  char* ws = (char*)d_ws;
  size_t off = 0;
  auto carve = [&](size_t bytes) {
    char* p = ws + off;
    off = (off + bytes + 255) & ~255ULL;
    return p;
  };
  int*   srcv   = (int*)carve((size_t)E * 4);
  int*   dstv   = (int*)carve((size_t)E * 4);
  int*   csr    = (int*)carve((size_t)E * 4);
  int*   cnt    = (int*)carve((size_t)N * 4);
  int*   rowptr = (int*)carve((size_t)(N + 1) * 4);
  int*   cursor = (int*)carve((size_t)N * 4);
  float* dnv    = (float*)carve((size_t)N * 4);
  int*   bsum   = (int*)carve((size_t)4096 * 4);
  int*   flag   = (int*)carve(4);
  unsigned short* W1h = (unsigned short*)carve(16384 * 2);
  unsigned short* W1l = (unsigned short*)carve(16384 * 2);
  unsigned short* W2h = (unsigned short*)carve(16384 * 2);
  unsigned short* W2l = (unsigned short*)carve(16384 * 2);
  float* bufA   = (float*)carve((size_t)N * NF * 4);
  float* bufB   = (float*)carve((size_t)N * NF * 4);

  int nblk = (N + 255) / 256;  // 391 for N=100000 (<=512 for scan_top)
  int mmblk = (N + 63) / 64;

  hipLaunchKernelGGL(init_detect_k, dim3(nblk), dim3(256), 0, stream, ei, 1024, N, flag, cnt);
  hipLaunchKernelGGL(decode_hist_k, dim3(2048), dim3(256), 0, stream, ei, E, N, flag, srcv, dstv, cnt);

  // CSR build
  hipLaunchKernelGGL(scan_block_k, dim3(nblk), dim3(256), 0, stream, cnt, rowptr, bsum, N);
  hipLaunchKernelGGL(scan_top_k, dim3(1), dim3(512), 0, stream, bsum, nblk);
  hipLaunchKernelGGL(scan_add_k, dim3(nblk), dim3(256), 0, stream, rowptr, bsum, cursor, cnt, dnv, N, E);
  hipLaunchKernelGGL(fill_k, dim3(2048), dim3(256), 0, stream, srcv, dstv, cursor, csr, E);

  // pack weights (both layers, one dispatch)
  hipLaunchKernelGGL(packW2_k, dim3(16), dim3(256), 0, stream, W1, W2, W1h, W1l, W2h, W2l);

  // layer 1
  hipLaunchKernelGGL(mm_mfma_k, dim3(mmblk), dim3(256), 0, stream, x, W1h, W1l, dnv, bufA, N);
  hipLaunchKernelGGL(gather_agg4_k, dim3(2048), dim3(256), 0, stream, rowptr, csr, dnv, bufA, b1, bufB, N);

  // layer 2 (+ fused final projection)
  hipLaunchKernelGGL(mm_mfma_k, dim3(mmblk), dim3(256), 0, stream, bufB, W2h, W2l, dnv, bufA, N);
  hipLaunchKernelGGL(gather_final4_k, dim3(2048), dim3(256), 0, stream, rowptr, csr, dnv, bufA, b2, Wl, bl, out, N);
}

// Round 8
// 547.406 us; speedup vs baseline: 5.7035x; 1.0968x over previous
//
#include <hip/hip_runtime.h>

#define NF 128

typedef __attribute__((ext_vector_type(8))) short short8v;
typedef __attribute__((ext_vector_type(4))) float f32x4;

__device__ __forceinline__ unsigned short f2bf(float x) {
  unsigned u = __builtin_bit_cast(unsigned, x);
  unsigned r = (u + 0x7FFFu + ((u >> 16) & 1u)) >> 16;
  return (unsigned short)r;
}
__device__ __forceinline__ float bf2f(unsigned short h) {
  unsigned u = ((unsigned)h) << 16;
  return __builtin_bit_cast(float, u);
}

// ---------------- zero cnt + dtype detect (merged) ----------------
__global__ void init_detect_k(const void* __restrict__ ei, int n_check, int N,
                              int* __restrict__ flag, int* __restrict__ cnt) {
  int i = blockIdx.x * blockDim.x + threadIdx.x;
  if (i < N) cnt[i] = 0;
  if (blockIdx.x == 0) {
    __shared__ int c;
    if (threadIdx.x == 0) c = 0;
    __syncthreads();
    const long long* p = (const long long*)ei;
    int good = 0;
    for (int k = threadIdx.x; k < n_check; k += blockDim.x) {
      long long v = p[k];
      if (v >= 0 && v < (long long)N) good++;
    }
    atomicAdd(&c, good);
    __syncthreads();
    if (threadIdx.x == 0) flag[0] = (c > n_check / 2) ? 1 : 0;
  }
}

// ---------------- decode + degree histogram (fused) ----------------
__global__ void decode_hist_k(const void* __restrict__ ei, int E, int N,
                              const int* __restrict__ flag,
                              int* __restrict__ src, int* __restrict__ dst,
                              int* __restrict__ cnt) {
  int is64 = flag[0];
  int stride = gridDim.x * blockDim.x;
  for (int e = blockIdx.x * blockDim.x + threadIdx.x; e < E; e += stride) {
    int s, d;
    if (is64) {
      s = (int)((const long long*)ei)[e];
      d = (int)((const long long*)ei)[(size_t)E + e];
    } else {
      s = ((const int*)ei)[e];
      d = ((const int*)ei)[(size_t)E + e];
    }
    s = min(max(s, 0), N - 1);
    d = min(max(d, 0), N - 1);
    src[e] = s;
    dst[e] = d;
    atomicAdd(&cnt[d], 1);
  }
}

// ---------------- scan for CSR rowptr ----------------
__global__ __launch_bounds__(256) void scan_block_k(const int* __restrict__ cnt,
                                                    int* __restrict__ rowptr,
                                                    int* __restrict__ bsum, int N) {
  __shared__ int tmp[256];
  int i = blockIdx.x * 256 + threadIdx.x;
  int v = (i < N) ? cnt[i] : 0;
  tmp[threadIdx.x] = v;
  __syncthreads();
  for (int o = 1; o < 256; o <<= 1) {
    int t = (threadIdx.x >= o) ? tmp[threadIdx.x - o] : 0;
    __syncthreads();
    tmp[threadIdx.x] += t;
    __syncthreads();
  }
  if (i < N) rowptr[i] = tmp[threadIdx.x] - v;  // exclusive
  if (threadIdx.x == 255) bsum[blockIdx.x] = tmp[255];
}

__global__ __launch_bounds__(512) void scan_top_k(int* __restrict__ bsum, int nb) {
  __shared__ int tmp[512];
  int v = (threadIdx.x < nb) ? bsum[threadIdx.x] : 0;
  tmp[threadIdx.x] = v;
  __syncthreads();
  for (int o = 1; o < 512; o <<= 1) {
    int t = (threadIdx.x >= o) ? tmp[threadIdx.x - o] : 0;
    __syncthreads();
    tmp[threadIdx.x] += t;
    __syncthreads();
  }
  if (threadIdx.x < nb) bsum[threadIdx.x] = tmp[threadIdx.x] - v;  // exclusive
}

__global__ void scan_add_k(int* __restrict__ rowptr, const int* __restrict__ bsum,
                           int* __restrict__ cursor, const int* __restrict__ cnt,
                           float* __restrict__ dinv, int N, int E) {
  int i = blockIdx.x * blockDim.x + threadIdx.x;
  if (i < N) {
    int r = rowptr[i] + bsum[i >> 8];
    rowptr[i] = r;
    cursor[i] = r;
    dinv[i] = rsqrtf((float)cnt[i] + 1.0f);  // +1 self-loop
  }
  if (i == 0) rowptr[N] = E;
}

// ---- team-partitioned fill: team t (blockIdx&3) fills dst range [t*R,(t+1)*R) ----
// csr stores confined to ~1.6MB span per team -> L2-resident, no line thrash.
__global__ void fill_k(const int* __restrict__ src, const int* __restrict__ dst,
                       int* __restrict__ cursor, int* __restrict__ csr, int E, int N) {
  int team = blockIdx.x & 3;
  int R = (N + 3) >> 2;
  int lo = team * R;
  int hi = min(N, lo + R);
  int sub = blockIdx.x >> 2;
  int nsub = gridDim.x >> 2;
  int stride = nsub * blockDim.x;
  for (int e = sub * blockDim.x + threadIdx.x; e < E; e += stride) {
    int d = dst[e];
    if (d >= lo && d < hi) {
      int pos = atomicAdd(&cursor[d], 1);
      csr[pos] = src[e];
    }
  }
}

// ---------------- pack W1,W2 into MFMA B-fragment order (hi/lo bf16) ----------------
// frag-lane t in [0,2048): ct=t>>8, kc=(t>>6)&3, lane=t&63
// element e: B[k = kc*32 + 8*(lane>>4) + e][col = ct*16 + (lane&15)]
__global__ void packW2_k(const float* __restrict__ W1, const float* __restrict__ W2,
                         unsigned short* __restrict__ PH1, unsigned short* __restrict__ PL1,
                         unsigned short* __restrict__ PH2, unsigned short* __restrict__ PL2) {
  int t = blockIdx.x * blockDim.x + threadIdx.x;
  if (t >= 4096) return;
  const float* W = (t < 2048) ? W1 : W2;
  unsigned short* PH = (t < 2048) ? PH1 : PH2;
  unsigned short* PL = (t < 2048) ? PL1 : PL2;
  int tt = t & 2047;
  int ct = tt >> 8, kc = (tt >> 6) & 3, lane = tt & 63;
  int k0 = kc * 32 + 8 * (lane >> 4);
  int col = ct * 16 + (lane & 15);
#pragma unroll
  for (int e = 0; e < 8; ++e) {
    float w = W[(size_t)(k0 + e) * NF + col];
    unsigned short h = f2bf(w);
    float lo = w - bf2f(h);
    PH[(size_t)tt * 8 + e] = h;
    PL[(size_t)tt * 8 + e] = f2bf(lo);
  }
}

// ---------------- MFMA matmul: Y = (X @ W) * dinv[row], bf16x3 split ----------------
__global__ __launch_bounds__(256) void mm_mfma_k(const float* __restrict__ X,
                                                 const unsigned short* __restrict__ WPH,
                                                 const unsigned short* __restrict__ WPL,
                                                 const float* __restrict__ dinv,
                                                 float* __restrict__ Y, int N) {
  int lane = threadIdx.x & 63;
  int wv = threadIdx.x >> 6;
  int row0 = blockIdx.x * 64 + wv * 16;
  if (row0 >= N) return;
  int ar = min(row0 + (lane & 15), N - 1);
  const float* xp = X + (size_t)ar * NF + 8 * (lane >> 4);
  short8v Ah[4], Al[4];
#pragma unroll
  for (int kc = 0; kc < 4; ++kc) {
    float4 v0 = *(const float4*)(xp + kc * 32);
    float4 v1 = *(const float4*)(xp + kc * 32 + 4);
    float xv[8] = {v0.x, v0.y, v0.z, v0.w, v1.x, v1.y, v1.z, v1.w};
#pragma unroll
    for (int e = 0; e < 8; ++e) {
      unsigned short h = f2bf(xv[e]);
      float lo = xv[e] - bf2f(h);
      Ah[kc][e] = (short)h;
      Al[kc][e] = (short)f2bf(lo);
    }
  }
  int rbase = row0 + (lane >> 4) * 4;
  float dv[4];
#pragma unroll
  for (int j = 0; j < 4; ++j) dv[j] = (rbase + j < N) ? dinv[rbase + j] : 0.f;
  const short8v* BH = (const short8v*)WPH;
  const short8v* BL = (const short8v*)WPL;
  int c = (lane & 15);
#pragma unroll
  for (int ct = 0; ct < 8; ++ct) {
    f32x4 acc = {0.f, 0.f, 0.f, 0.f};
#pragma unroll
    for (int kc = 0; kc < 4; ++kc) {
      short8v bh = BH[(ct * 4 + kc) * 64 + lane];
      short8v bl = BL[(ct * 4 + kc) * 64 + lane];
      acc = __builtin_amdgcn_mfma_f32_16x16x32_bf16(Ah[kc], bh, acc, 0, 0, 0);
      acc = __builtin_amdgcn_mfma_f32_16x16x32_bf16(Ah[kc], bl, acc, 0, 0, 0);
      acc = __builtin_amdgcn_mfma_f32_16x16x32_bf16(Al[kc], bh, acc, 0, 0, 0);
    }
#pragma unroll
    for (int j = 0; j < 4; ++j) {
      int r = rbase + j;
      if (r < N) Y[(size_t)r * NF + ct * 16 + c] = acc[j] * dv[j];
    }
  }
}

// ------- gather aggregate (float4, 2 rows/wave): OUT[d,:] = relu(dinv[d]*(G[d,:]+sum G[s,:])+b) -------
__global__ __launch_bounds__(256) void gather_agg4_k(const int* __restrict__ rowptr,
                                                     const int* __restrict__ csr,
                                                     const float* __restrict__ dinv,
                                                     const float* __restrict__ G,
                                                     const float* __restrict__ b,
                                                     float* __restrict__ OUT, int N) {
  int lane = threadIdx.x & 63;
  int half = lane >> 5;
  int l32  = lane & 31;
  int w    = blockIdx.x * 4 + (threadIdx.x >> 6);
  int nw   = gridDim.x * 4;
  const float4* G4 = (const float4*)G;
  float4 bv = ((const float4*)b)[l32];
  for (int d0 = w * 2; d0 < N; d0 += nw * 2) {
    int d = d0 + half;
    if (d < N) {
      int beg = rowptr[d], end = rowptr[d + 1];
      float4 acc = G4[(size_t)d * 32 + l32];  // self-loop (already *dinv[d])
      int cnt = end - beg;
      int j = 0;
      while (j < cnt) {
        int chunk = min(cnt - j, 32);
        int idx = (l32 < chunk) ? csr[beg + j + l32] : 0;
        int t = 0;
        for (; t + 8 <= chunk; t += 8) {
          int s0 = __shfl(idx, t + 0, 32);
          int s1 = __shfl(idx, t + 1, 32);
          int s2 = __shfl(idx, t + 2, 32);
          int s3 = __shfl(idx, t + 3, 32);
          int s4 = __shfl(idx, t + 4, 32);
          int s5 = __shfl(idx, t + 5, 32);
          int s6 = __shfl(idx, t + 6, 32);
          int s7 = __shfl(idx, t + 7, 32);
          float4 v0 = G4[(size_t)s0 * 32 + l32];
          float4 v1 = G4[(size_t)s1 * 32 + l32];
          float4 v2 = G4[(size_t)s2 * 32 + l32];
          float4 v3 = G4[(size_t)s3 * 32 + l32];
          float4 v4 = G4[(size_t)s4 * 32 + l32];
          float4 v5 = G4[(size_t)s5 * 32 + l32];
          float4 v6 = G4[(size_t)s6 * 32 + l32];
          float4 v7 = G4[(size_t)s7 * 32 + l32];
          acc.x += (v0.x + v1.x) + (v2.x + v3.x) + ((v4.x + v5.x) + (v6.x + v7.x));
          acc.y += (v0.y + v1.y) + (v2.y + v3.y) + ((v4.y + v5.y) + (v6.y + v7.y));
          acc.z += (v0.z + v1.z) + (v2.z + v3.z) + ((v4.z + v5.z) + (v6.z + v7.z));
          acc.w += (v0.w + v1.w) + (v2.w + v3.w) + ((v4.w + v5.w) + (v6.w + v7.w));
        }
        for (; t < chunk; ++t) {
          int s = __shfl(idx, t, 32);
          float4 v = G4[(size_t)s * 32 + l32];
          acc.x += v.x; acc.y += v.y; acc.z += v.z; acc.w += v.w;
        }
        j += chunk;
      }
      float dd = dinv[d];
      float4 o;
      o.x = fmaxf(acc.x * dd + bv.x, 0.f);
      o.y = fmaxf(acc.y * dd + bv.y, 0.f);
      o.z = fmaxf(acc.z * dd + bv.z, 0.f);
      o.w = fmaxf(acc.w * dd + bv.w, 0.f);
      ((float4*)OUT)[(size_t)d * 32 + l32] = o;
    }
  }
}

// ------- layer-2 gather fused with final projection: out[d] = dot(relu(...), Wl) + bl -------
__global__ __launch_bounds__(256) void gather_final4_k(const int* __restrict__ rowptr,
                                                       const int* __restrict__ csr,
                                                       const float* __restrict__ dinv,
                                                       const float* __restrict__ G,
                                                       const float* __restrict__ b,
                                                       const float* __restrict__ Wl,
                                                       const float* __restrict__ bl,
                                                       float* __restrict__ out, int N) {
  int lane = threadIdx.x & 63;
  int half = lane >> 5;
  int l32  = lane & 31;
  int w    = blockIdx.x * 4 + (threadIdx.x >> 6);
  int nw   = gridDim.x * 4;
  const float4* G4 = (const float4*)G;
  float4 bv = ((const float4*)b)[l32];
  float4 wv = ((const float4*)Wl)[l32];
  float blv = bl[0];
  for (int d0 = w * 2; d0 < N; d0 += nw * 2) {
    int d = d0 + half;
    if (d < N) {
      int beg = rowptr[d], end = rowptr[d + 1];
      float4 acc = G4[(size_t)d * 32 + l32];
      int cnt = end - beg;
      int j = 0;
      while (j < cnt) {
        int chunk = min(cnt - j, 32);
        int idx = (l32 < chunk) ? csr[beg + j + l32] : 0;
        int t = 0;
        for (; t + 8 <= chunk; t += 8) {
          int s0 = __shfl(idx, t + 0, 32);
          int s1 = __shfl(idx, t + 1, 32);
          int s2 = __shfl(idx, t + 2, 32);
          int s3 = __shfl(idx, t + 3, 32);
          int s4 = __shfl(idx, t + 4, 32);
          int s5 = __shfl(idx, t + 5, 32);
          int s6 = __shfl(idx, t + 6, 32);
          int s7 = __shfl(idx, t + 7, 32);
          float4 v0 = G4[(size_t)s0 * 32 + l32];
          float4 v1 = G4[(size_t)s1 * 32 + l32];
          float4 v2 = G4[(size_t)s2 * 32 + l32];
          float4 v3 = G4[(size_t)s3 * 32 + l32];
          float4 v4 = G4[(size_t)s4 * 32 + l32];
          float4 v5 = G4[(size_t)s5 * 32 + l32];
          float4 v6 = G4[(size_t)s6 * 32 + l32];
          float4 v7 = G4[(size_t)s7 * 32 + l32];
          acc.x += (v0.x + v1.x) + (v2.x + v3.x) + ((v4.x + v5.x) + (v6.x + v7.x));
          acc.y += (v0.y + v1.y) + (v2.y + v3.y) + ((v4.y + v5.y) + (v6.y + v7.y));
          acc.z += (v0.z + v1.z) + (v2.z + v3.z) + ((v4.z + v5.z) + (v6.z + v7.z));
          acc.w += (v0.w + v1.w) + (v2.w + v3.w) + ((v4.w + v5.w) + (v6.w + v7.w));
        }
        for (; t < chunk; ++t) {
          int s = __shfl(idx, t, 32);
          float4 v = G4[(size_t)s * 32 + l32];
          acc.x += v.x; acc.y += v.y; acc.z += v.z; acc.w += v.w;
        }
        j += chunk;
      }
      float dd = dinv[d];
      float p = fmaxf(acc.x * dd + bv.x, 0.f) * wv.x
              + fmaxf(acc.y * dd + bv.y, 0.f) * wv.y
              + fmaxf(acc.z * dd + bv.z, 0.f) * wv.z
              + fmaxf(acc.w * dd + bv.w, 0.f) * wv.w;
#pragma unroll
      for (int off = 16; off; off >>= 1) p += __shfl_xor(p, off, 32);
      if (l32 == 0) out[d] = p + blv;
    }
  }
}

extern "C" void kernel_launch(void* const* d_in, const int* in_sizes, int n_in,
                              void* d_out, int out_size, void* d_ws, size_t ws_size,
                              hipStream_t stream) {
  const float* x  = (const float*)d_in[0];
  const void*  ei = d_in[1];
  const float* W1 = (const float*)d_in[2];
  const float* b1 = (const float*)d_in[3];
  const float* W2 = (const float*)d_in[4];
  const float* b2 = (const float*)d_in[5];
  const float* Wl = (const float*)d_in[6];
  const float* bl = (const float*)d_in[7];
  float* out = (float*)d_out;

  int N = in_sizes[0] / NF;
  int E = in_sizes[1] / 2;

  char* ws = (char*)d_ws;
  size_t off = 0;
  auto carve = [&](size_t bytes) {
    char* p = ws + off;
    off = (off + bytes + 255) & ~255ULL;
    return p;
  };
  int*   srcv   = (int*)carve((size_t)E * 4);
  int*   dstv   = (int*)carve((size_t)E * 4);
  int*   csr    = (int*)carve((size_t)E * 4);
  int*   cnt    = (int*)carve((size_t)N * 4);
  int*   rowptr = (int*)carve((size_t)(N + 1) * 4);
  int*   cursor = (int*)carve((size_t)N * 4);
  float* dnv    = (float*)carve((size_t)N * 4);
  int*   bsum   = (int*)carve((size_t)4096 * 4);
  int*   flag   = (int*)carve(4);
  unsigned short* W1h = (unsigned short*)carve(16384 * 2);
  unsigned short* W1l = (unsigned short*)carve(16384 * 2);
  unsigned short* W2h = (unsigned short*)carve(16384 * 2);
  unsigned short* W2l = (unsigned short*)carve(16384 * 2);
  float* bufA   = (float*)carve((size_t)N * NF * 4);
  float* bufB   = (float*)carve((size_t)N * NF * 4);

  int nblk = (N + 255) / 256;  // 391 for N=100000 (<=512 for scan_top)
  int mmblk = (N + 63) / 64;

  hipLaunchKernelGGL(init_detect_k, dim3(nblk), dim3(256), 0, stream, ei, 1024, N, flag, cnt);
  hipLaunchKernelGGL(decode_hist_k, dim3(2048), dim3(256), 0, stream, ei, E, N, flag, srcv, dstv, cnt);

  // CSR build
  hipLaunchKernelGGL(scan_block_k, dim3(nblk), dim3(256), 0, stream, cnt, rowptr, bsum, N);
  hipLaunchKernelGGL(scan_top_k, dim3(1), dim3(512), 0, stream, bsum, nblk);
  hipLaunchKernelGGL(scan_add_k, dim3(nblk), dim3(256), 0, stream, rowptr, bsum, cursor, cnt, dnv, N, E);
  hipLaunchKernelGGL(fill_k, dim3(2048), dim3(256), 0, stream, srcv, dstv, cursor, csr, E, N);

  // pack weights (both layers, one dispatch)
  hipLaunchKernelGGL(packW2_k, dim3(16), dim3(256), 0, stream, W1, W2, W1h, W1l, W2h, W2l);

  // layer 1
  hipLaunchKernelGGL(mm_mfma_k, dim3(mmblk), dim3(256), 0, stream, x, W1h, W1l, dnv, bufA, N);
  hipLaunchKernelGGL(gather_agg4_k, dim3(2048), dim3(256), 0, stream, rowptr, csr, dnv, bufA, b1, bufB, N);

  // layer 2 (+ fused final projection)
  hipLaunchKernelGGL(mm_mfma_k, dim3(mmblk), dim3(256), 0, stream, bufB, W2h, W2l, dnv, bufA, N);
  hipLaunchKernelGGL(gather_final4_k, dim3(2048), dim3(256), 0, stream, rowptr, csr, dnv, bufA, b2, Wl, bl, out, N);
}

// Round 9
// 426.721 us; speedup vs baseline: 7.3166x; 1.2828x over previous
//
#include <hip/hip_runtime.h>

#define NF 128

typedef __attribute__((ext_vector_type(8))) short short8v;
typedef __attribute__((ext_vector_type(4))) float f32x4;

__device__ __forceinline__ unsigned short f2bf(float x) {
  unsigned u = __builtin_bit_cast(unsigned, x);
  unsigned r = (u + 0x7FFFu + ((u >> 16) & 1u)) >> 16;
  return (unsigned short)r;
}
__device__ __forceinline__ float bf2f(unsigned short h) {
  unsigned u = ((unsigned)h) << 16;
  return __builtin_bit_cast(float, u);
}
// unpack 4 bf16 (packed in uint2) -> float4
__device__ __forceinline__ float4 bfx4(uint2 v) {
  float4 r;
  r.x = __builtin_bit_cast(float, v.x << 16);
  r.y = __builtin_bit_cast(float, v.x & 0xffff0000u);
  r.z = __builtin_bit_cast(float, v.y << 16);
  r.w = __builtin_bit_cast(float, v.y & 0xffff0000u);
  return r;
}

// ---------------- zero cnt + dtype detect (merged) ----------------
__global__ void init_detect_k(const void* __restrict__ ei, int n_check, int N,
                              int* __restrict__ flag, int* __restrict__ cnt) {
  int i = blockIdx.x * blockDim.x + threadIdx.x;
  if (i < N) cnt[i] = 0;
  if (blockIdx.x == 0) {
    __shared__ int c;
    if (threadIdx.x == 0) c = 0;
    __syncthreads();
    const long long* p = (const long long*)ei;
    int good = 0;
    for (int k = threadIdx.x; k < n_check; k += blockDim.x) {
      long long v = p[k];
      if (v >= 0 && v < (long long)N) good++;
    }
    atomicAdd(&c, good);
    __syncthreads();
    if (threadIdx.x == 0) flag[0] = (c > n_check / 2) ? 1 : 0;
  }
}

// ---------------- decode + degree histogram (fused) ----------------
__global__ void decode_hist_k(const void* __restrict__ ei, int E, int N,
                              const int* __restrict__ flag,
                              int* __restrict__ src, int* __restrict__ dst,
                              int* __restrict__ cnt) {
  int is64 = flag[0];
  int stride = gridDim.x * blockDim.x;
  for (int e = blockIdx.x * blockDim.x + threadIdx.x; e < E; e += stride) {
    int s, d;
    if (is64) {
      s = (int)((const long long*)ei)[e];
      d = (int)((const long long*)ei)[(size_t)E + e];
    } else {
      s = ((const int*)ei)[e];
      d = ((const int*)ei)[(size_t)E + e];
    }
    s = min(max(s, 0), N - 1);
    d = min(max(d, 0), N - 1);
    src[e] = s;
    dst[e] = d;
    atomicAdd(&cnt[d], 1);
  }
}

// ---------------- scan for CSR rowptr ----------------
__global__ __launch_bounds__(256) void scan_block_k(const int* __restrict__ cnt,
                                                    int* __restrict__ rowptr,
                                                    int* __restrict__ bsum, int N) {
  __shared__ int tmp[256];
  int i = blockIdx.x * 256 + threadIdx.x;
  int v = (i < N) ? cnt[i] : 0;
  tmp[threadIdx.x] = v;
  __syncthreads();
  for (int o = 1; o < 256; o <<= 1) {
    int t = (threadIdx.x >= o) ? tmp[threadIdx.x - o] : 0;
    __syncthreads();
    tmp[threadIdx.x] += t;
    __syncthreads();
  }
  if (i < N) rowptr[i] = tmp[threadIdx.x] - v;  // exclusive
  if (threadIdx.x == 255) bsum[blockIdx.x] = tmp[255];
}

__global__ __launch_bounds__(512) void scan_top_k(int* __restrict__ bsum, int nb) {
  __shared__ int tmp[512];
  int v = (threadIdx.x < nb) ? bsum[threadIdx.x] : 0;
  tmp[threadIdx.x] = v;
  __syncthreads();
  for (int o = 1; o < 512; o <<= 1) {
    int t = (threadIdx.x >= o) ? tmp[threadIdx.x - o] : 0;
    __syncthreads();
    tmp[threadIdx.x] += t;
    __syncthreads();
  }
  if (threadIdx.x < nb) bsum[threadIdx.x] = tmp[threadIdx.x] - v;  // exclusive
}

__global__ void scan_add_k(int* __restrict__ rowptr, const int* __restrict__ bsum,
                           int* __restrict__ cursor, const int* __restrict__ cnt,
                           float* __restrict__ dinv, int N, int E) {
  int i = blockIdx.x * blockDim.x + threadIdx.x;
  if (i < N) {
    int r = rowptr[i] + bsum[i >> 8];
    rowptr[i] = r;
    cursor[i] = r;
    dinv[i] = rsqrtf((float)cnt[i] + 1.0f);  // +1 self-loop
  }
  if (i == 0) rowptr[N] = E;
}

// ---- team-partitioned fill: team t (blockIdx&3) fills dst range [t*R,(t+1)*R) ----
__global__ void fill_k(const int* __restrict__ src, const int* __restrict__ dst,
                       int* __restrict__ cursor, int* __restrict__ csr, int E, int N) {
  int team = blockIdx.x & 3;
  int R = (N + 3) >> 2;
  int lo = team * R;
  int hi = min(N, lo + R);
  int sub = blockIdx.x >> 2;
  int nsub = gridDim.x >> 2;
  int stride = nsub * blockDim.x;
  for (int e = sub * blockDim.x + threadIdx.x; e < E; e += stride) {
    int d = dst[e];
    if (d >= lo && d < hi) {
      int pos = atomicAdd(&cursor[d], 1);
      csr[pos] = src[e];
    }
  }
}

// ---------------- pack W1,W2 into MFMA B-fragment order (hi/lo bf16) ----------------
__global__ void packW2_k(const float* __restrict__ W1, const float* __restrict__ W2,
                         unsigned short* __restrict__ PH1, unsigned short* __restrict__ PL1,
                         unsigned short* __restrict__ PH2, unsigned short* __restrict__ PL2) {
  int t = blockIdx.x * blockDim.x + threadIdx.x;
  if (t >= 4096) return;
  const float* W = (t < 2048) ? W1 : W2;
  unsigned short* PH = (t < 2048) ? PH1 : PH2;
  unsigned short* PL = (t < 2048) ? PL1 : PL2;
  int tt = t & 2047;
  int ct = tt >> 8, kc = (tt >> 6) & 3, lane = tt & 63;
  int k0 = kc * 32 + 8 * (lane >> 4);
  int col = ct * 16 + (lane & 15);
#pragma unroll
  for (int e = 0; e < 8; ++e) {
    float w = W[(size_t)(k0 + e) * NF + col];
    unsigned short h = f2bf(w);
    float lo = w - bf2f(h);
    PH[(size_t)tt * 8 + e] = h;
    PL[(size_t)tt * 8 + e] = f2bf(lo);
  }
}

// ------- MFMA matmul: Yb[r,c] = bf16( (X @ W)[r,c] * dinv[r] ), bf16x3 split -------
__global__ __launch_bounds__(256) void mm_mfma_k(const float* __restrict__ X,
                                                 const unsigned short* __restrict__ WPH,
                                                 const unsigned short* __restrict__ WPL,
                                                 const float* __restrict__ dinv,
                                                 unsigned short* __restrict__ Yb, int N) {
  int lane = threadIdx.x & 63;
  int wv = threadIdx.x >> 6;
  int row0 = blockIdx.x * 64 + wv * 16;
  if (row0 >= N) return;
  int ar = min(row0 + (lane & 15), N - 1);
  const float* xp = X + (size_t)ar * NF + 8 * (lane >> 4);
  short8v Ah[4], Al[4];
#pragma unroll
  for (int kc = 0; kc < 4; ++kc) {
    float4 v0 = *(const float4*)(xp + kc * 32);
    float4 v1 = *(const float4*)(xp + kc * 32 + 4);
    float xv[8] = {v0.x, v0.y, v0.z, v0.w, v1.x, v1.y, v1.z, v1.w};
#pragma unroll
    for (int e = 0; e < 8; ++e) {
      unsigned short h = f2bf(xv[e]);
      float lo = xv[e] - bf2f(h);
      Ah[kc][e] = (short)h;
      Al[kc][e] = (short)f2bf(lo);
    }
  }
  int rbase = row0 + (lane >> 4) * 4;
  float dv[4];
#pragma unroll
  for (int j = 0; j < 4; ++j) dv[j] = (rbase + j < N) ? dinv[rbase + j] : 0.f;
  const short8v* BH = (const short8v*)WPH;
  const short8v* BL = (const short8v*)WPL;
  int c = (lane & 15);
#pragma unroll
  for (int ct = 0; ct < 8; ++ct) {
    f32x4 acc = {0.f, 0.f, 0.f, 0.f};
#pragma unroll
    for (int kc = 0; kc < 4; ++kc) {
      short8v bh = BH[(ct * 4 + kc) * 64 + lane];
      short8v bl = BL[(ct * 4 + kc) * 64 + lane];
      acc = __builtin_amdgcn_mfma_f32_16x16x32_bf16(Ah[kc], bh, acc, 0, 0, 0);
      acc = __builtin_amdgcn_mfma_f32_16x16x32_bf16(Ah[kc], bl, acc, 0, 0, 0);
      acc = __builtin_amdgcn_mfma_f32_16x16x32_bf16(Al[kc], bh, acc, 0, 0, 0);
    }
#pragma unroll
    for (int j = 0; j < 4; ++j) {
      int r = rbase + j;
      if (r < N) Yb[(size_t)r * NF + ct * 16 + c] = f2bf(acc[j] * dv[j]);
    }
  }
}

// ------- gather aggregate (bf16 G, 2 rows/wave): OUT[d,:] = relu(dinv[d]*(G[d,:]+sum G[s,:])+b) -------
__global__ __launch_bounds__(256) void gather_agg4_k(const int* __restrict__ rowptr,
                                                     const int* __restrict__ csr,
                                                     const float* __restrict__ dinv,
                                                     const unsigned short* __restrict__ G,
                                                     const float* __restrict__ b,
                                                     float* __restrict__ OUT, int N) {
  int lane = threadIdx.x & 63;
  int half = lane >> 5;
  int l32  = lane & 31;
  int w    = blockIdx.x * 4 + (threadIdx.x >> 6);
  int nw   = gridDim.x * 4;
  const uint2* G2 = (const uint2*)G;
  float4 bv = ((const float4*)b)[l32];
  for (int d0 = w * 2; d0 < N; d0 += nw * 2) {
    int d = d0 + half;
    if (d < N) {
      int beg = rowptr[d], end = rowptr[d + 1];
      float4 sf = bfx4(G2[(size_t)d * 32 + l32]);  // self-loop (already *dinv[d])
      float4 acc = sf;
      int cnt = end - beg;
      int j = 0;
      while (j < cnt) {
        int chunk = min(cnt - j, 32);
        int idx = (l32 < chunk) ? csr[beg + j + l32] : 0;
        int t = 0;
        for (; t + 8 <= chunk; t += 8) {
          int s0 = __shfl(idx, t + 0, 32);
          int s1 = __shfl(idx, t + 1, 32);
          int s2 = __shfl(idx, t + 2, 32);
          int s3 = __shfl(idx, t + 3, 32);
          int s4 = __shfl(idx, t + 4, 32);
          int s5 = __shfl(idx, t + 5, 32);
          int s6 = __shfl(idx, t + 6, 32);
          int s7 = __shfl(idx, t + 7, 32);
          float4 v0 = bfx4(G2[(size_t)s0 * 32 + l32]);
          float4 v1 = bfx4(G2[(size_t)s1 * 32 + l32]);
          float4 v2 = bfx4(G2[(size_t)s2 * 32 + l32]);
          float4 v3 = bfx4(G2[(size_t)s3 * 32 + l32]);
          float4 v4 = bfx4(G2[(size_t)s4 * 32 + l32]);
          float4 v5 = bfx4(G2[(size_t)s5 * 32 + l32]);
          float4 v6 = bfx4(G2[(size_t)s6 * 32 + l32]);
          float4 v7 = bfx4(G2[(size_t)s7 * 32 + l32]);
          acc.x += (v0.x + v1.x) + (v2.x + v3.x) + ((v4.x + v5.x) + (v6.x + v7.x));
          acc.y += (v0.y + v1.y) + (v2.y + v3.y) + ((v4.y + v5.y) + (v6.y + v7.y));
          acc.z += (v0.z + v1.z) + (v2.z + v3.z) + ((v4.z + v5.z) + (v6.z + v7.z));
          acc.w += (v0.w + v1.w) + (v2.w + v3.w) + ((v4.w + v5.w) + (v6.w + v7.w));
        }
        for (; t < chunk; ++t) {
          int s = __shfl(idx, t, 32);
          float4 v = bfx4(G2[(size_t)s * 32 + l32]);
          acc.x += v.x; acc.y += v.y; acc.z += v.z; acc.w += v.w;
        }
        j += chunk;
      }
      float dd = dinv[d];
      float4 o;
      o.x = fmaxf(acc.x * dd + bv.x, 0.f);
      o.y = fmaxf(acc.y * dd + bv.y, 0.f);
      o.z = fmaxf(acc.z * dd + bv.z, 0.f);
      o.w = fmaxf(acc.w * dd + bv.w, 0.f);
      ((float4*)OUT)[(size_t)d * 32 + l32] = o;
    }
  }
}

// ------- layer-2 gather (bf16 G) fused with final projection: out[d] = dot(relu(...), Wl) + bl -------
__global__ __launch_bounds__(256) void gather_final4_k(const int* __restrict__ rowptr,
                                                       const int* __restrict__ csr,
                                                       const float* __restrict__ dinv,
                                                       const unsigned short* __restrict__ G,
                                                       const float* __restrict__ b,
                                                       const float* __restrict__ Wl,
                                                       const float* __restrict__ bl,
                                                       float* __restrict__ out, int N) {
  int lane = threadIdx.x & 63;
  int half = lane >> 5;
  int l32  = lane & 31;
  int w    = blockIdx.x * 4 + (threadIdx.x >> 6);
  int nw   = gridDim.x * 4;
  const uint2* G2 = (const uint2*)G;
  float4 bv = ((const float4*)b)[l32];
  float4 wv = ((const float4*)Wl)[l32];
  float blv = bl[0];
  for (int d0 = w * 2; d0 < N; d0 += nw * 2) {
    int d = d0 + half;
    if (d < N) {
      int beg = rowptr[d], end = rowptr[d + 1];
      float4 acc = bfx4(G2[(size_t)d * 32 + l32]);
      int cnt = end - beg;
      int j = 0;
      while (j < cnt) {
        int chunk = min(cnt - j, 32);
        int idx = (l32 < chunk) ? csr[beg + j + l32] : 0;
        int t = 0;
        for (; t + 8 <= chunk; t += 8) {
          int s0 = __shfl(idx, t + 0, 32);
          int s1 = __shfl(idx, t + 1, 32);
          int s2 = __shfl(idx, t + 2, 32);
          int s3 = __shfl(idx, t + 3, 32);
          int s4 = __shfl(idx, t + 4, 32);
          int s5 = __shfl(idx, t + 5, 32);
          int s6 = __shfl(idx, t + 6, 32);
          int s7 = __shfl(idx, t + 7, 32);
          float4 v0 = bfx4(G2[(size_t)s0 * 32 + l32]);
          float4 v1 = bfx4(G2[(size_t)s1 * 32 + l32]);
          float4 v2 = bfx4(G2[(size_t)s2 * 32 + l32]);
          float4 v3 = bfx4(G2[(size_t)s3 * 32 + l32]);
          float4 v4 = bfx4(G2[(size_t)s4 * 32 + l32]);
          float4 v5 = bfx4(G2[(size_t)s5 * 32 + l32]);
          float4 v6 = bfx4(G2[(size_t)s6 * 32 + l32]);
          float4 v7 = bfx4(G2[(size_t)s7 * 32 + l32]);
          acc.x += (v0.x + v1.x) + (v2.x + v3.x) + ((v4.x + v5.x) + (v6.x + v7.x));
          acc.y += (v0.y + v1.y) + (v2.y + v3.y) + ((v4.y + v5.y) + (v6.y + v7.y));
          acc.z += (v0.z + v1.z) + (v2.z + v3.z) + ((v4.z + v5.z) + (v6.z + v7.z));
          acc.w += (v0.w + v1.w) + (v2.w + v3.w) + ((v4.w + v5.w) + (v6.w + v7.w));
        }
        for (; t < chunk; ++t) {
          int s = __shfl(idx, t, 32);
          float4 v = bfx4(G2[(size_t)s * 32 + l32]);
          acc.x += v.x; acc.y += v.y; acc.z += v.z; acc.w += v.w;
        }
        j += chunk;
      }
      float dd = dinv[d];
      float p = fmaxf(acc.x * dd + bv.x, 0.f) * wv.x
              + fmaxf(acc.y * dd + bv.y, 0.f) * wv.y
              + fmaxf(acc.z * dd + bv.z, 0.f) * wv.z
              + fmaxf(acc.w * dd + bv.w, 0.f) * wv.w;
#pragma unroll
      for (int off = 16; off; off >>= 1) p += __shfl_xor(p, off, 32);
      if (l32 == 0) out[d] = p + blv;
    }
  }
}

extern "C" void kernel_launch(void* const* d_in, const int* in_sizes, int n_in,
                              void* d_out, int out_size, void* d_ws, size_t ws_size,
                              hipStream_t stream) {
  const float* x  = (const float*)d_in[0];
  const void*  ei = d_in[1];
  const float* W1 = (const float*)d_in[2];
  const float* b1 = (const float*)d_in[3];
  const float* W2 = (const float*)d_in[4];
  const float* b2 = (const float*)d_in[5];
  const float* Wl = (const float*)d_in[6];
  const float* bl = (const float*)d_in[7];
  float* out = (float*)d_out;

  int N = in_sizes[0] / NF;
  int E = in_sizes[1] / 2;

  char* ws = (char*)d_ws;
  size_t off = 0;
  auto carve = [&](size_t bytes) {
    char* p = ws + off;
    off = (off + bytes + 255) & ~255ULL;
    return p;
  };
  int*   srcv   = (int*)carve((size_t)E * 4);
  int*   dstv   = (int*)carve((size_t)E * 4);
  int*   csr    = (int*)carve((size_t)E * 4);
  int*   cnt    = (int*)carve((size_t)N * 4);
  int*   rowptr = (int*)carve((size_t)(N + 1) * 4);
  int*   cursor = (int*)carve((size_t)N * 4);
  float* dnv    = (float*)carve((size_t)N * 4);
  int*   bsum   = (int*)carve((size_t)4096 * 4);
  int*   flag   = (int*)carve(4);
  unsigned short* W1h = (unsigned short*)carve(16384 * 2);
  unsigned short* W1l = (unsigned short*)carve(16384 * 2);
  unsigned short* W2h = (unsigned short*)carve(16384 * 2);
  unsigned short* W2l = (unsigned short*)carve(16384 * 2);
  unsigned short* bufG = (unsigned short*)carve((size_t)N * NF * 2);  // bf16 G
  float*          bufH = (float*)carve((size_t)N * NF * 4);           // fp32 hidden

  int nblk = (N + 255) / 256;  // 391 for N=100000 (<=512 for scan_top)
  int mmblk = (N + 63) / 64;

  hipLaunchKernelGGL(init_detect_k, dim3(nblk), dim3(256), 0, stream, ei, 1024, N, flag, cnt);
  hipLaunchKernelGGL(decode_hist_k, dim3(2048), dim3(256), 0, stream, ei, E, N, flag, srcv, dstv, cnt);

  // CSR build
  hipLaunchKernelGGL(scan_block_k, dim3(nblk), dim3(256), 0, stream, cnt, rowptr, bsum, N);
  hipLaunchKernelGGL(scan_top_k, dim3(1), dim3(512), 0, stream, bsum, nblk);
  hipLaunchKernelGGL(scan_add_k, dim3(nblk), dim3(256), 0, stream, rowptr, bsum, cursor, cnt, dnv, N, E);
  hipLaunchKernelGGL(fill_k, dim3(2048), dim3(256), 0, stream, srcv, dstv, cursor, csr, E, N);

  // pack weights (both layers, one dispatch)
  hipLaunchKernelGGL(packW2_k, dim3(16), dim3(256), 0, stream, W1, W2, W1h, W1l, W2h, W2l);

  // layer 1
  hipLaunchKernelGGL(mm_mfma_k, dim3(mmblk), dim3(256), 0, stream, x, W1h, W1l, dnv, bufG, N);
  hipLaunchKernelGGL(gather_agg4_k, dim3(2048), dim3(256), 0, stream, rowptr, csr, dnv, bufG, b1, bufH, N);

  // layer 2 (+ fused final projection)
  hipLaunchKernelGGL(mm_mfma_k, dim3(mmblk), dim3(256), 0, stream, bufH, W2h, W2l, dnv, bufG, N);
  hipLaunchKernelGGL(gather_final4_k, dim3(2048), dim3(256), 0, stream, rowptr, csr, dnv, bufG, b2, Wl, bl, out, N);
}

// Round 10
// 412.880 us; speedup vs baseline: 7.5619x; 1.0335x over previous
//
#include <hip/hip_runtime.h>

#define NF 128

typedef __attribute__((ext_vector_type(8))) short short8v;
typedef __attribute__((ext_vector_type(4))) float f32x4;

__device__ __forceinline__ unsigned short f2bf(float x) {
  unsigned u = __builtin_bit_cast(unsigned, x);
  unsigned r = (u + 0x7FFFu + ((u >> 16) & 1u)) >> 16;
  return (unsigned short)r;
}
__device__ __forceinline__ float bf2f(unsigned short h) {
  unsigned u = ((unsigned)h) << 16;
  return __builtin_bit_cast(float, u);
}
// unpack 4 bf16 (packed in uint2) -> float4
__device__ __forceinline__ float4 bfx4(uint2 v) {
  float4 r;
  r.x = __builtin_bit_cast(float, v.x << 16);
  r.y = __builtin_bit_cast(float, v.x & 0xffff0000u);
  r.z = __builtin_bit_cast(float, v.y << 16);
  r.w = __builtin_bit_cast(float, v.y & 0xffff0000u);
  return r;
}
__device__ __forceinline__ uint2 packbf4(float4 o) {
  uint2 p;
  p.x = (unsigned)f2bf(o.x) | ((unsigned)f2bf(o.y) << 16);
  p.y = (unsigned)f2bf(o.z) | ((unsigned)f2bf(o.w) << 16);
  return p;
}

// ---------------- zero cnt + dtype detect (merged) ----------------
__global__ void init_detect_k(const void* __restrict__ ei, int n_check, int N,
                              int* __restrict__ flag, int* __restrict__ cnt) {
  int i = blockIdx.x * blockDim.x + threadIdx.x;
  if (i < N) cnt[i] = 0;
  if (blockIdx.x == 0) {
    __shared__ int c;
    if (threadIdx.x == 0) c = 0;
    __syncthreads();
    const long long* p = (const long long*)ei;
    int good = 0;
    for (int k = threadIdx.x; k < n_check; k += blockDim.x) {
      long long v = p[k];
      if (v >= 0 && v < (long long)N) good++;
    }
    atomicAdd(&c, good);
    __syncthreads();
    if (threadIdx.x == 0) flag[0] = (c > n_check / 2) ? 1 : 0;
  }
}

// ---------------- decode + degree histogram (fused) ----------------
__global__ void decode_hist_k(const void* __restrict__ ei, int E, int N,
                              const int* __restrict__ flag,
                              int* __restrict__ src, int* __restrict__ dst,
                              int* __restrict__ cnt) {
  int is64 = flag[0];
  int stride = gridDim.x * blockDim.x;
  for (int e = blockIdx.x * blockDim.x + threadIdx.x; e < E; e += stride) {
    int s, d;
    if (is64) {
      s = (int)((const long long*)ei)[e];
      d = (int)((const long long*)ei)[(size_t)E + e];
    } else {
      s = ((const int*)ei)[e];
      d = ((const int*)ei)[(size_t)E + e];
    }
    s = min(max(s, 0), N - 1);
    d = min(max(d, 0), N - 1);
    src[e] = s;
    dst[e] = d;
    atomicAdd(&cnt[d], 1);
  }
}

// ---------------- scan for CSR rowptr ----------------
__global__ __launch_bounds__(256) void scan_block_k(const int* __restrict__ cnt,
                                                    int* __restrict__ rowptr,
                                                    int* __restrict__ bsum, int N) {
  __shared__ int tmp[256];
  int i = blockIdx.x * 256 + threadIdx.x;
  int v = (i < N) ? cnt[i] : 0;
  tmp[threadIdx.x] = v;
  __syncthreads();
  for (int o = 1; o < 256; o <<= 1) {
    int t = (threadIdx.x >= o) ? tmp[threadIdx.x - o] : 0;
    __syncthreads();
    tmp[threadIdx.x] += t;
    __syncthreads();
  }
  if (i < N) rowptr[i] = tmp[threadIdx.x] - v;  // exclusive
  if (threadIdx.x == 255) bsum[blockIdx.x] = tmp[255];
}

__global__ __launch_bounds__(512) void scan_top_k(int* __restrict__ bsum, int nb) {
  __shared__ int tmp[512];
  int v = (threadIdx.x < nb) ? bsum[threadIdx.x] : 0;
  tmp[threadIdx.x] = v;
  __syncthreads();
  for (int o = 1; o < 512; o <<= 1) {
    int t = (threadIdx.x >= o) ? tmp[threadIdx.x - o] : 0;
    __syncthreads();
    tmp[threadIdx.x] += t;
    __syncthreads();
  }
  if (threadIdx.x < nb) bsum[threadIdx.x] = tmp[threadIdx.x] - v;  // exclusive
}

__global__ void scan_add_k(int* __restrict__ rowptr, const int* __restrict__ bsum,
                           int* __restrict__ cursor, const int* __restrict__ cnt,
                           float* __restrict__ dinv, int N, int E) {
  int i = blockIdx.x * blockDim.x + threadIdx.x;
  if (i < N) {
    int r = rowptr[i] + bsum[i >> 8];
    rowptr[i] = r;
    cursor[i] = r;
    dinv[i] = rsqrtf((float)cnt[i] + 1.0f);  // +1 self-loop
  }
  if (i == 0) rowptr[N] = E;
}

// ---- 8-team fill: team t (blockIdx&7) fills dst range [t*R,(t+1)*R) ----
// With round-robin block->XCD dispatch, each team's csr span (~0.8MB) is
// built inside a single XCD's L2 -> no cross-XCD dirty-line duplication.
__global__ void fill_k(const int* __restrict__ src, const int* __restrict__ dst,
                       int* __restrict__ cursor, int* __restrict__ csr, int E, int N) {
  int team = blockIdx.x & 7;
  int R = (N + 7) >> 3;
  int lo = team * R;
  int hi = min(N, lo + R);
  int sub = blockIdx.x >> 3;
  int nsub = gridDim.x >> 3;
  int stride = nsub * blockDim.x;
  for (int e = sub * blockDim.x + threadIdx.x; e < E; e += stride) {
    int d = dst[e];
    if (d >= lo && d < hi) {
      int pos = atomicAdd(&cursor[d], 1);
      csr[pos] = src[e];
    }
  }
}

// ---------------- pack W1,W2 into MFMA B-fragment order (hi/lo bf16) ----------------
__global__ void packW2_k(const float* __restrict__ W1, const float* __restrict__ W2,
                         unsigned short* __restrict__ PH1, unsigned short* __restrict__ PL1,
                         unsigned short* __restrict__ PH2, unsigned short* __restrict__ PL2) {
  int t = blockIdx.x * blockDim.x + threadIdx.x;
  if (t >= 4096) return;
  const float* W = (t < 2048) ? W1 : W2;
  unsigned short* PH = (t < 2048) ? PH1 : PH2;
  unsigned short* PL = (t < 2048) ? PL1 : PL2;
  int tt = t & 2047;
  int ct = tt >> 8, kc = (tt >> 6) & 3, lane = tt & 63;
  int k0 = kc * 32 + 8 * (lane >> 4);
  int col = ct * 16 + (lane & 15);
#pragma unroll
  for (int e = 0; e < 8; ++e) {
    float w = W[(size_t)(k0 + e) * NF + col];
    unsigned short h = f2bf(w);
    float lo = w - bf2f(h);
    PH[(size_t)tt * 8 + e] = h;
    PL[(size_t)tt * 8 + e] = f2bf(lo);
  }
}

// ------- MFMA matmul (fp32 in): Yb[r,c] = bf16((X @ W)[r,c] * dinv[r]), bf16x3 -------
__global__ __launch_bounds__(256) void mm_mfma_k(const float* __restrict__ X,
                                                 const unsigned short* __restrict__ WPH,
                                                 const unsigned short* __restrict__ WPL,
                                                 const float* __restrict__ dinv,
                                                 unsigned short* __restrict__ Yb, int N) {
  int lane = threadIdx.x & 63;
  int wv = threadIdx.x >> 6;
  int row0 = blockIdx.x * 64 + wv * 16;
  if (row0 >= N) return;
  int ar = min(row0 + (lane & 15), N - 1);
  const float* xp = X + (size_t)ar * NF + 8 * (lane >> 4);
  short8v Ah[4], Al[4];
#pragma unroll
  for (int kc = 0; kc < 4; ++kc) {
    float4 v0 = *(const float4*)(xp + kc * 32);
    float4 v1 = *(const float4*)(xp + kc * 32 + 4);
    float xv[8] = {v0.x, v0.y, v0.z, v0.w, v1.x, v1.y, v1.z, v1.w};
#pragma unroll
    for (int e = 0; e < 8; ++e) {
      unsigned short h = f2bf(xv[e]);
      float lo = xv[e] - bf2f(h);
      Ah[kc][e] = (short)h;
      Al[kc][e] = (short)f2bf(lo);
    }
  }
  int rbase = row0 + (lane >> 4) * 4;
  float dv[4];
#pragma unroll
  for (int j = 0; j < 4; ++j) dv[j] = (rbase + j < N) ? dinv[rbase + j] : 0.f;
  const short8v* BH = (const short8v*)WPH;
  const short8v* BL = (const short8v*)WPL;
  int c = (lane & 15);
#pragma unroll
  for (int ct = 0; ct < 8; ++ct) {
    f32x4 acc = {0.f, 0.f, 0.f, 0.f};
#pragma unroll
    for (int kc = 0; kc < 4; ++kc) {
      short8v bh = BH[(ct * 4 + kc) * 64 + lane];
      short8v bl = BL[(ct * 4 + kc) * 64 + lane];
      acc = __builtin_amdgcn_mfma_f32_16x16x32_bf16(Ah[kc], bh, acc, 0, 0, 0);
      acc = __builtin_amdgcn_mfma_f32_16x16x32_bf16(Ah[kc], bl, acc, 0, 0, 0);
      acc = __builtin_amdgcn_mfma_f32_16x16x32_bf16(Al[kc], bh, acc, 0, 0, 0);
    }
#pragma unroll
    for (int j = 0; j < 4; ++j) {
      int r = rbase + j;
      if (r < N) Yb[(size_t)r * NF + ct * 16 + c] = f2bf(acc[j] * dv[j]);
    }
  }
}

// ------- MFMA matmul (bf16 in): A already bf16 -> no lo-split, 2 MFMAs/tile -------
__global__ __launch_bounds__(256) void mm_mfma_b_k(const unsigned short* __restrict__ Xb,
                                                   const unsigned short* __restrict__ WPH,
                                                   const unsigned short* __restrict__ WPL,
                                                   const float* __restrict__ dinv,
                                                   unsigned short* __restrict__ Yb, int N) {
  int lane = threadIdx.x & 63;
  int wv = threadIdx.x >> 6;
  int row0 = blockIdx.x * 64 + wv * 16;
  if (row0 >= N) return;
  int ar = min(row0 + (lane & 15), N - 1);
  const unsigned short* xp = Xb + (size_t)ar * NF + 8 * (lane >> 4);
  short8v Ah[4];
#pragma unroll
  for (int kc = 0; kc < 4; ++kc) Ah[kc] = *(const short8v*)(xp + kc * 32);
  int rbase = row0 + (lane >> 4) * 4;
  float dv[4];
#pragma unroll
  for (int j = 0; j < 4; ++j) dv[j] = (rbase + j < N) ? dinv[rbase + j] : 0.f;
  const short8v* BH = (const short8v*)WPH;
  const short8v* BL = (const short8v*)WPL;
  int c = (lane & 15);
#pragma unroll
  for (int ct = 0; ct < 8; ++ct) {
    f32x4 acc = {0.f, 0.f, 0.f, 0.f};
#pragma unroll
    for (int kc = 0; kc < 4; ++kc) {
      short8v bh = BH[(ct * 4 + kc) * 64 + lane];
      short8v bl = BL[(ct * 4 + kc) * 64 + lane];
      acc = __builtin_amdgcn_mfma_f32_16x16x32_bf16(Ah[kc], bh, acc, 0, 0, 0);
      acc = __builtin_amdgcn_mfma_f32_16x16x32_bf16(Ah[kc], bl, acc, 0, 0, 0);
    }
#pragma unroll
    for (int j = 0; j < 4; ++j) {
      int r = rbase + j;
      if (r < N) Yb[(size_t)r * NF + ct * 16 + c] = f2bf(acc[j] * dv[j]);
    }
  }
}

// ------- gather aggregate (bf16 G -> bf16 H): H[d,:] = relu(dinv[d]*(G[d,:]+sum G[s,:])+b) -------
__global__ __launch_bounds__(256) void gather_agg4_k(const int* __restrict__ rowptr,
                                                     const int* __restrict__ csr,
                                                     const float* __restrict__ dinv,
                                                     const unsigned short* __restrict__ G,
                                                     const float* __restrict__ b,
                                                     unsigned short* __restrict__ OUT, int N) {
  int lane = threadIdx.x & 63;
  int half = lane >> 5;
  int l32  = lane & 31;
  int w    = blockIdx.x * 4 + (threadIdx.x >> 6);
  int nw   = gridDim.x * 4;
  const uint2* G2 = (const uint2*)G;
  float4 bv = ((const float4*)b)[l32];
  for (int d0 = w * 2; d0 < N; d0 += nw * 2) {
    int d = d0 + half;
    if (d < N) {
      int beg = rowptr[d], end = rowptr[d + 1];
      float4 acc = bfx4(G2[(size_t)d * 32 + l32]);  // self-loop (already *dinv[d])
      int cnt = end - beg;
      int j = 0;
      while (j < cnt) {
        int chunk = min(cnt - j, 32);
        int idx = (l32 < chunk) ? csr[beg + j + l32] : 0;
        int t = 0;
        for (; t + 8 <= chunk; t += 8) {
          int s0 = __shfl(idx, t + 0, 32);
          int s1 = __shfl(idx, t + 1, 32);
          int s2 = __shfl(idx, t + 2, 32);
          int s3 = __shfl(idx, t + 3, 32);
          int s4 = __shfl(idx, t + 4, 32);
          int s5 = __shfl(idx, t + 5, 32);
          int s6 = __shfl(idx, t + 6, 32);
          int s7 = __shfl(idx, t + 7, 32);
          float4 v0 = bfx4(G2[(size_t)s0 * 32 + l32]);
          float4 v1 = bfx4(G2[(size_t)s1 * 32 + l32]);
          float4 v2 = bfx4(G2[(size_t)s2 * 32 + l32]);
          float4 v3 = bfx4(G2[(size_t)s3 * 32 + l32]);
          float4 v4 = bfx4(G2[(size_t)s4 * 32 + l32]);
          float4 v5 = bfx4(G2[(size_t)s5 * 32 + l32]);
          float4 v6 = bfx4(G2[(size_t)s6 * 32 + l32]);
          float4 v7 = bfx4(G2[(size_t)s7 * 32 + l32]);
          acc.x += (v0.x + v1.x) + (v2.x + v3.x) + ((v4.x + v5.x) + (v6.x + v7.x));
          acc.y += (v0.y + v1.y) + (v2.y + v3.y) + ((v4.y + v5.y) + (v6.y + v7.y));
          acc.z += (v0.z + v1.z) + (v2.z + v3.z) + ((v4.z + v5.z) + (v6.z + v7.z));
          acc.w += (v0.w + v1.w) + (v2.w + v3.w) + ((v4.w + v5.w) + (v6.w + v7.w));
        }
        for (; t < chunk; ++t) {
          int s = __shfl(idx, t, 32);
          float4 v = bfx4(G2[(size_t)s * 32 + l32]);
          acc.x += v.x; acc.y += v.y; acc.z += v.z; acc.w += v.w;
        }
        j += chunk;
      }
      float dd = dinv[d];
      float4 o;
      o.x = fmaxf(acc.x * dd + bv.x, 0.f);
      o.y = fmaxf(acc.y * dd + bv.y, 0.f);
      o.z = fmaxf(acc.z * dd + bv.z, 0.f);
      o.w = fmaxf(acc.w * dd + bv.w, 0.f);
      ((uint2*)OUT)[(size_t)d * 32 + l32] = packbf4(o);
    }
  }
}

// ------- layer-2 gather (bf16 G) fused with final projection: out[d] = dot(relu(...), Wl) + bl -------
__global__ __launch_bounds__(256) void gather_final4_k(const int* __restrict__ rowptr,
                                                       const int* __restrict__ csr,
                                                       const float* __restrict__ dinv,
                                                       const unsigned short* __restrict__ G,
                                                       const float* __restrict__ b,
                                                       const float* __restrict__ Wl,
                                                       const float* __restrict__ bl,
                                                       float* __restrict__ out, int N) {
  int lane = threadIdx.x & 63;
  int half = lane >> 5;
  int l32  = lane & 31;
  int w    = blockIdx.x * 4 + (threadIdx.x >> 6);
  int nw   = gridDim.x * 4;
  const uint2* G2 = (const uint2*)G;
  float4 bv = ((const float4*)b)[l32];
  float4 wv = ((const float4*)Wl)[l32];
  float blv = bl[0];
  for (int d0 = w * 2; d0 < N; d0 += nw * 2) {
    int d = d0 + half;
    if (d < N) {
      int beg = rowptr[d], end = rowptr[d + 1];
      float4 acc = bfx4(G2[(size_t)d * 32 + l32]);
      int cnt = end - beg;
      int j = 0;
      while (j < cnt) {
        int chunk = min(cnt - j, 32);
        int idx = (l32 < chunk) ? csr[beg + j + l32] : 0;
        int t = 0;
        for (; t + 8 <= chunk; t += 8) {
          int s0 = __shfl(idx, t + 0, 32);
          int s1 = __shfl(idx, t + 1, 32);
          int s2 = __shfl(idx, t + 2, 32);
          int s3 = __shfl(idx, t + 3, 32);
          int s4 = __shfl(idx, t + 4, 32);
          int s5 = __shfl(idx, t + 5, 32);
          int s6 = __shfl(idx, t + 6, 32);
          int s7 = __shfl(idx, t + 7, 32);
          float4 v0 = bfx4(G2[(size_t)s0 * 32 + l32]);
          float4 v1 = bfx4(G2[(size_t)s1 * 32 + l32]);
          float4 v2 = bfx4(G2[(size_t)s2 * 32 + l32]);
          float4 v3 = bfx4(G2[(size_t)s3 * 32 + l32]);
          float4 v4 = bfx4(G2[(size_t)s4 * 32 + l32]);
          float4 v5 = bfx4(G2[(size_t)s5 * 32 + l32]);
          float4 v6 = bfx4(G2[(size_t)s6 * 32 + l32]);
          float4 v7 = bfx4(G2[(size_t)s7 * 32 + l32]);
          acc.x += (v0.x + v1.x) + (v2.x + v3.x) + ((v4.x + v5.x) + (v6.x + v7.x));
          acc.y += (v0.y + v1.y) + (v2.y + v3.y) + ((v4.y + v5.y) + (v6.y + v7.y));
          acc.z += (v0.z + v1.z) + (v2.z + v3.z) + ((v4.z + v5.z) + (v6.z + v7.z));
          acc.w += (v0.w + v1.w) + (v2.w + v3.w) + ((v4.w + v5.w) + (v6.w + v7.w));
        }
        for (; t < chunk; ++t) {
          int s = __shfl(idx, t, 32);
          float4 v = bfx4(G2[(size_t)s * 32 + l32]);
          acc.x += v.x; acc.y += v.y; acc.z += v.z; acc.w += v.w;
        }
        j += chunk;
      }
      float dd = dinv[d];
      float p = fmaxf(acc.x * dd + bv.x, 0.f) * wv.x
              + fmaxf(acc.y * dd + bv.y, 0.f) * wv.y
              + fmaxf(acc.z * dd + bv.z, 0.f) * wv.z
              + fmaxf(acc.w * dd + bv.w, 0.f) * wv.w;
#pragma unroll
      for (int off = 16; off; off >>= 1) p += __shfl_xor(p, off, 32);
      if (l32 == 0) out[d] = p + blv;
    }
  }
}

extern "C" void kernel_launch(void* const* d_in, const int* in_sizes, int n_in,
                              void* d_out, int out_size, void* d_ws, size_t ws_size,
                              hipStream_t stream) {
  const float* x  = (const float*)d_in[0];
  const void*  ei = d_in[1];
  const float* W1 = (const float*)d_in[2];
  const float* b1 = (const float*)d_in[3];
  const float* W2 = (const float*)d_in[4];
  const float* b2 = (const float*)d_in[5];
  const float* Wl = (const float*)d_in[6];
  const float* bl = (const float*)d_in[7];
  float* out = (float*)d_out;

  int N = in_sizes[0] / NF;
  int E = in_sizes[1] / 2;

  char* ws = (char*)d_ws;
  size_t off = 0;
  auto carve = [&](size_t bytes) {
    char* p = ws + off;
    off = (off + bytes + 255) & ~255ULL;
    return p;
  };
  int*   srcv   = (int*)carve((size_t)E * 4);
  int*   dstv   = (int*)carve((size_t)E * 4);
  int*   csr    = (int*)carve((size_t)E * 4);
  int*   cnt    = (int*)carve((size_t)N * 4);
  int*   rowptr = (int*)carve((size_t)(N + 1) * 4);
  int*   cursor = (int*)carve((size_t)N * 4);
  float* dnv    = (float*)carve((size_t)N * 4);
  int*   bsum   = (int*)carve((size_t)4096 * 4);
  int*   flag   = (int*)carve(4);
  unsigned short* W1h = (unsigned short*)carve(16384 * 2);
  unsigned short* W1l = (unsigned short*)carve(16384 * 2);
  unsigned short* W2h = (unsigned short*)carve(16384 * 2);
  unsigned short* W2l = (unsigned short*)carve(16384 * 2);
  unsigned short* bufG = (unsigned short*)carve((size_t)N * NF * 2);  // bf16 G
  unsigned short* bufH = (unsigned short*)carve((size_t)N * NF * 2);  // bf16 hidden

  int nblk = (N + 255) / 256;  // 391 for N=100000 (<=512 for scan_top)
  int mmblk = (N + 63) / 64;

  hipLaunchKernelGGL(init_detect_k, dim3(nblk), dim3(256), 0, stream, ei, 1024, N, flag, cnt);
  hipLaunchKernelGGL(decode_hist_k, dim3(2048), dim3(256), 0, stream, ei, E, N, flag, srcv, dstv, cnt);

  // CSR build
  hipLaunchKernelGGL(scan_block_k, dim3(nblk), dim3(256), 0, stream, cnt, rowptr, bsum, N);
  hipLaunchKernelGGL(scan_top_k, dim3(1), dim3(512), 0, stream, bsum, nblk);
  hipLaunchKernelGGL(scan_add_k, dim3(nblk), dim3(256), 0, stream, rowptr, bsum, cursor, cnt, dnv, N, E);
  hipLaunchKernelGGL(fill_k, dim3(2048), dim3(256), 0, stream, srcv, dstv, cursor, csr, E, N);

  // pack weights (both layers, one dispatch)
  hipLaunchKernelGGL(packW2_k, dim3(16), dim3(256), 0, stream, W1, W2, W1h, W1l, W2h, W2l);

  // layer 1
  hipLaunchKernelGGL(mm_mfma_k, dim3(mmblk), dim3(256), 0, stream, x, W1h, W1l, dnv, bufG, N);
  hipLaunchKernelGGL(gather_agg4_k, dim3(2048), dim3(256), 0, stream, rowptr, csr, dnv, bufG, b1, bufH, N);

  // layer 2 (+ fused final projection)
  hipLaunchKernelGGL(mm_mfma_b_k, dim3(mmblk), dim3(256), 0, stream, bufH, W2h, W2l, dnv, bufG, N);
  hipLaunchKernelGGL(gather_final4_k, dim3(2048), dim3(256), 0, stream, rowptr, csr, dnv, bufG, b2, Wl, bl, out, N);
}